// Round 1
// 967.295 us; speedup vs baseline: 1.0006x; 1.0006x over previous
//
#include <hip/hip_runtime.h>
#include <hip/hip_bf16.h>

#define N_NODES 50000
#define N_EDGES 500000
#define DIM_A 128
#define DIM_V 32
#define CHAN 32
#define EB 64            // edges per block in edge kernel
#define SCAN_B 49        // ceil(50000/1024)

typedef __attribute__((ext_vector_type(8))) short short8;
typedef __attribute__((ext_vector_type(8))) unsigned short ushort8;
typedef __attribute__((ext_vector_type(4))) float f32x4;
typedef unsigned short ushort;

__device__ __forceinline__ ushort f2bf(float x) {
    __hip_bfloat16 h = __float2bfloat16(x);
    return *reinterpret_cast<ushort*>(&h);
}
__device__ __forceinline__ float bf2f(ushort u) {
    union { float f; unsigned int i; } v; v.i = ((unsigned int)u) << 16; return v.f;
}
__device__ __forceinline__ float leaky(float x) {
    return x >= 0.f ? x : 0.1f * x;
}

// ---------------- weight conversion ----------------
__global__ __launch_bounds__(256) void convw_kernel(
    const float* __restrict__ Wy000, const float* __restrict__ Wy110,
    const float* __restrict__ Wy011, const float* __restrict__ Wy101,
    const float* __restrict__ Wy111,
    const float* __restrict__ Wm1, const float* __restrict__ Wm2,
    const float* __restrict__ Wm3,
    ushort* __restrict__ W0b, ushort* __restrict__ Wm1b,
    ushort* __restrict__ Wm2b, ushort* __restrict__ Wm3b,
    ushort* __restrict__ W011b, ushort* __restrict__ W101b,
    ushort* __restrict__ W111b)
{
    int g = blockIdx.x * 256 + threadIdx.x;
    if (g < 128 * 64) {           // W0b[o][c]: c<32 -> Wy000, else Wy110
        int o = g >> 6, c = g & 63;
        float v = (c < 32) ? Wy000[o * 32 + c] : Wy110[o * 32 + (c - 32)];
        W0b[g] = f2bf(v);
    }
    if (g < 128 * 128) {
        Wm1b[g] = f2bf(Wm1[g]);
        Wm2b[g] = f2bf(Wm2[g]);
        Wm3b[g] = f2bf(Wm3[g]);
    }
    if (g < 32 * 32) {
        W011b[g] = f2bf(Wy011[g]);
        W101b[g] = f2bf(Wy101[g]);
        W111b[g] = f2bf(Wy111[g]);
    }
}

// ---------------- node projection: LN[n][128] = [L0(32) | L1(96, c*3+i)] ----
__global__ __launch_bounds__(256) void node_proj_kernel(
    const float* __restrict__ x_a, const float* __restrict__ x_v,
    const float* __restrict__ W_L0, const float* __restrict__ W_L1,
    float* __restrict__ LN)
{
    int t = threadIdx.x;
    int n = blockIdx.x * 8 + (t >> 5);
    int c = t & 31;
    if (n >= N_NODES) return;

    const float4* xa = (const float4*)(x_a + (size_t)n * DIM_A);
    const float4* w0 = (const float4*)(W_L0 + c * DIM_A);
    float acc = 0.f;
#pragma unroll 8
    for (int k = 0; k < DIM_A / 4; ++k) {
        float4 x = xa[k]; float4 w = w0[k];
        acc += x.x * w.x + x.y * w.y + x.z * w.z + x.w * w.w;
    }
    LN[(size_t)n * 128 + c] = acc;

    const float* xv = x_v + (size_t)n * DIM_V * 3;
    const float* w1 = W_L1 + c * DIM_V;
    float a0 = 0.f, a1 = 0.f, a2 = 0.f;
#pragma unroll 8
    for (int d = 0; d < DIM_V; ++d) {
        float w = w1[d];
        a0 += xv[d * 3 + 0] * w;
        a1 += xv[d * 3 + 1] * w;
        a2 += xv[d * 3 + 2] * w;
    }
    float* o = LN + (size_t)n * 128 + 32 + c * 3;
    o[0] = a0; o[1] = a1; o[2] = a2;
}

// ---------------- dual histogram ----------------
__global__ __launch_bounds__(256) void hist2_kernel(
    const int* __restrict__ src, const int* __restrict__ dst,
    int* __restrict__ degS, int* __restrict__ degD)
{
    int i = blockIdx.x * 256 + threadIdx.x;
    if (i < N_EDGES) {
        atomicAdd(&degS[src[i]], 1);
        atomicAdd(&degD[dst[i]], 1);
    }
}

// ---------------- 3-phase multi-block exclusive scan ----------------
__global__ __launch_bounds__(1024) void scan1_kernel(const int* __restrict__ deg,
                                                     int* __restrict__ excl,
                                                     int* __restrict__ bsum)
{
    __shared__ int buf[1024];
    int t = threadIdx.x;
    int i = blockIdx.x * 1024 + t;
    int v = (i < N_NODES) ? deg[i] : 0;
    buf[t] = v;
    __syncthreads();
    for (int off = 1; off < 1024; off <<= 1) {
        int x = (t >= off) ? buf[t - off] : 0;
        __syncthreads();
        buf[t] += x;
        __syncthreads();
    }
    if (i < N_NODES) excl[i] = buf[t] - v;
    if (t == 1023) bsum[blockIdx.x] = buf[1023];
}

__global__ void scan2_kernel(int* __restrict__ bsum)
{
    if (threadIdx.x == 0) {
        int s = 0;
        for (int k = 0; k < SCAN_B; ++k) { int x = bsum[k]; bsum[k] = s; s += x; }
    }
}

__global__ __launch_bounds__(1024) void scan3_kernel(const int* __restrict__ excl,
                                                     const int* __restrict__ bsum,
                                                     int* __restrict__ offs,
                                                     int* __restrict__ cursor)
{
    int t = threadIdx.x;
    int i = blockIdx.x * 1024 + t;
    if (i < N_NODES) {
        int o = excl[i] + bsum[blockIdx.x];
        offs[i] = o;
        cursor[i] = o;
    }
    if (i == 0) offs[N_NODES] = N_EDGES;
}

// ---------------- scatter: src slots, then dst-order packed edge records ----
__global__ __launch_bounds__(256) void scatterS_kernel(const int* __restrict__ src,
                                                       int* __restrict__ curS,
                                                       int* __restrict__ srcPos)
{
    int i = blockIdx.x * 256 + threadIdx.x;
    if (i < N_EDGES) srcPos[i] = atomicAdd(&curS[src[i]], 1);
}

__global__ __launch_bounds__(256) void scatterD_kernel(
    const int* __restrict__ dst, const float* __restrict__ r_ij,
    const int* __restrict__ srcPos, int* __restrict__ curD,
    float4* __restrict__ edgeD, int* __restrict__ sposD)
{
    int i = blockIdx.x * 256 + threadIdx.x;
    if (i < N_EDGES) {
        int d = dst[i];
        int p = atomicAdd(&curD[d], 1);
        edgeD[p] = make_float4(r_ij[i * 3 + 0], r_ij[i * 3 + 1], r_ij[i * 3 + 2],
                               __int_as_float(d));
        sposD[p] = srcPos[i];
    }
}

// ---------------- MFMA edge kernel (barrier-free, dst-order, 4 blocks/CU) ---
// LDS exactly 40960 B: sY0 9216 + sRELV 13312 + sACT 17408 + sRS 1024.
// v2: psi outputs staged through sACT and stored as nontemporal dwordx4
// (64B segments) instead of 56 scattered 2B stores per thread; NT loads on
// streaming edge records. Goal: stop thrashing L2/L3 so weight/LN loads stay
// cache-resident (latency-bound kernel: all pipes <12% busy).
__global__ __launch_bounds__(256, 4) void edge_mfma_kernel(
    const float4* __restrict__ edgeD, const int* __restrict__ sposD,
    const float* __restrict__ LN,
    const float* __restrict__ W_enc, const float* __restrict__ b_enc,
    const ushort* __restrict__ W0b, const ushort* __restrict__ Wm1b,
    const ushort* __restrict__ Wm2b, const ushort* __restrict__ Wm3b,
    const ushort* __restrict__ W011b, const ushort* __restrict__ W101b,
    const ushort* __restrict__ W111b,
    const float* __restrict__ bm1, const float* __restrict__ bm2,
    ushort* __restrict__ psiA, ushort* __restrict__ psiV)
{
    __shared__ __align__(16) ushort sY0[64 * 72];     // [e][72]: 0..31 y000, 32..63 y110
    __shared__ __align__(16) ushort sRELV[64 * 104];  // [e][104]: i*32+c = re*lv_i
    __shared__ __align__(16) ushort sACT[64 * 136];   // [e][136] activations
    __shared__ __align__(16) float sRS[64 * 4];       // [e]: rsx,rsy,rsz,spos-bits

    const int t = threadIdx.x;
    const int e0 = blockIdx.x * EB;

    // ---- phase 1: per-edge features -> LDS (wave-row partitioned) ----
    {
        const int e = t >> 2;          // wave w owns e in [16w,16w+16)
        const int p = t & 3;           // 8 channels each
        const int qe = min(e0 + e, N_EDGES - 1);
        f32x4 edv = __builtin_nontemporal_load((const f32x4*)edgeD + qe);
        int spos = __builtin_nontemporal_load(sposD + qe);
        float rx = edv[0], ry = edv[1], rz = edv[2];
        int dn = __float_as_int(edv[3]);
        float r = sqrtf(rx * rx + ry * ry + rz * rz);

        float rad[8];
#pragma unroll
        for (int k = 0; k < 8; ++k) {
            float d = (r - (5.0f / 7.0f) * (float)k) * 1.6f;
            rad[k] = expf(-d * d);
        }
        float n14 = 1.4f * r;
        float tt = tanhf(n14) / fmaxf(n14, 1e-6f);
        float rsx = 1.4f * rx * tt, rsy = 1.4f * ry * tt, rsz = 1.4f * rz * tt;
        if (p == 0) {
            *(float4*)&sRS[e * 4] = make_float4(rsx, rsy, rsz, __int_as_float(spos));
        }

        float la[8];
        {
            const float4* lap = (const float4*)(LN + (size_t)dn * 128 + p * 8);
            float4 A = lap[0], B = lap[1];
            la[0] = A.x; la[1] = A.y; la[2] = A.z; la[3] = A.w;
            la[4] = B.x; la[5] = B.y; la[6] = B.z; la[7] = B.w;
        }
        float lv[24];
        {
            const float4* lvp = (const float4*)(LN + (size_t)dn * 128 + 32 + p * 24);
#pragma unroll
            for (int q = 0; q < 6; ++q) {
                float4 v = lvp[q];
                lv[q * 4 + 0] = v.x; lv[q * 4 + 1] = v.y;
                lv[q * 4 + 2] = v.z; lv[q * 4 + 3] = v.w;
            }
        }

        ushort8 u000, u110, url[3];
#pragma unroll
        for (int j = 0; j < 8; ++j) {
            int c = p * 8 + j;
            float re = b_enc[c];
#pragma unroll
            for (int k = 0; k < 8; ++k) re += rad[k] * W_enc[c * 8 + k];
            float lvx = lv[j * 3 + 0], lvy = lv[j * 3 + 1], lvz = lv[j * 3 + 2];
            float dotv = lvx * rsx + lvy * rsy + lvz * rsz;
            u000[j] = f2bf(la[j] * re);
            u110[j] = f2bf(re * dotv);
            url[0][j] = f2bf(re * lvx);
            url[1][j] = f2bf(re * lvy);
            url[2][j] = f2bf(re * lvz);
        }
        *(ushort8*)&sY0[e * 72 + p * 8]      = u000;
        *(ushort8*)&sY0[e * 72 + 32 + p * 8] = u110;
#pragma unroll
        for (int i = 0; i < 3; ++i)
            *(ushort8*)&sRELV[e * 104 + i * 32 + p * 8] = url[i];
    }
    // no barrier: same-wave LDS ordering via lgkmcnt

    // ---- phase 2: MFMA chain ----
    const int lane = t & 63;
    const int w = t >> 6;
    const int r0 = lane & 15;
    const int quad = lane >> 4;
    const int arow = w * 16 + r0;

    // psi0 = Y0 @ W0cat^T (K=64); fp32 residual in regs, bf16 to sACT
    f32x4 p0[8];
    {
        short8 aY[2];
        aY[0] = *(const short8*)&sY0[arow * 72 + quad * 8];
        aY[1] = *(const short8*)&sY0[arow * 72 + 32 + quad * 8];
#pragma unroll
        for (int nt = 0; nt < 8; ++nt) {
            f32x4 acc = {0.f, 0.f, 0.f, 0.f};
#pragma unroll
            for (int kb = 0; kb < 2; ++kb) {
                short8 b = *(const short8*)&W0b[(nt * 16 + r0) * 64 + kb * 32 + quad * 8];
                acc = __builtin_amdgcn_mfma_f32_16x16x32_bf16(aY[kb], b, acc, 0, 0, 0);
            }
            p0[nt] = acc;
#pragma unroll
            for (int rr = 0; rr < 4; ++rr)
                sACT[(w * 16 + quad * 4 + rr) * 136 + nt * 16 + r0] = f2bf(acc[rr]);
        }
    }

    // h1 = leaky(act @ Wm1^T + bm1)
    {
        short8 af[4];
#pragma unroll
        for (int kb = 0; kb < 4; ++kb)
            af[kb] = *(const short8*)&sACT[arow * 136 + kb * 32 + quad * 8];
        f32x4 hv[8];
#pragma unroll
        for (int nt = 0; nt < 8; ++nt) {
            float bv = bm1[nt * 16 + r0];
            f32x4 acc = {bv, bv, bv, bv};
#pragma unroll
            for (int kb = 0; kb < 4; ++kb) {
                short8 b = *(const short8*)&Wm1b[(nt * 16 + r0) * 128 + kb * 32 + quad * 8];
                acc = __builtin_amdgcn_mfma_f32_16x16x32_bf16(af[kb], b, acc, 0, 0, 0);
            }
#pragma unroll
            for (int rr = 0; rr < 4; ++rr) acc[rr] = leaky(acc[rr]);
            hv[nt] = acc;
        }
#pragma unroll
        for (int nt = 0; nt < 8; ++nt)
#pragma unroll
            for (int rr = 0; rr < 4; ++rr)
                sACT[(w * 16 + quad * 4 + rr) * 136 + nt * 16 + r0] = f2bf(hv[nt][rr]);
    }

    // h2 = leaky(act @ Wm2^T + bm2)
    {
        short8 af[4];
#pragma unroll
        for (int kb = 0; kb < 4; ++kb)
            af[kb] = *(const short8*)&sACT[arow * 136 + kb * 32 + quad * 8];
        f32x4 hv[8];
#pragma unroll
        for (int nt = 0; nt < 8; ++nt) {
            float bv = bm2[nt * 16 + r0];
            f32x4 acc = {bv, bv, bv, bv};
#pragma unroll
            for (int kb = 0; kb < 4; ++kb) {
                short8 b = *(const short8*)&Wm2b[(nt * 16 + r0) * 128 + kb * 32 + quad * 8];
                acc = __builtin_amdgcn_mfma_f32_16x16x32_bf16(af[kb], b, acc, 0, 0, 0);
            }
#pragma unroll
            for (int rr = 0; rr < 4; ++rr) acc[rr] = leaky(acc[rr]);
            hv[nt] = acc;
        }
#pragma unroll
        for (int nt = 0; nt < 8; ++nt)
#pragma unroll
            for (int rr = 0; rr < 4; ++rr)
                sACT[(w * 16 + quad * 4 + rr) * 136 + nt * 16 + r0] = f2bf(hv[nt][rr]);
    }

    // psi_a = psi0 + h2 @ Wm3^T -> sACT -> wide NT store to src-sorted slot
    {
        short8 af[4];
#pragma unroll
        for (int kb = 0; kb < 4; ++kb)
            af[kb] = *(const short8*)&sACT[arow * 136 + kb * 32 + quad * 8];
#pragma unroll
        for (int nt = 0; nt < 8; ++nt) {
            f32x4 acc = {0.f, 0.f, 0.f, 0.f};
#pragma unroll
            for (int kb = 0; kb < 4; ++kb) {
                short8 b = *(const short8*)&Wm3b[(nt * 16 + r0) * 128 + kb * 32 + quad * 8];
                acc = __builtin_amdgcn_mfma_f32_16x16x32_bf16(af[kb], b, acc, 0, 0, 0);
            }
#pragma unroll
            for (int rr = 0; rr < 4; ++rr)
                sACT[(w * 16 + quad * 4 + rr) * 136 + nt * 16 + r0] =
                    f2bf(acc[rr] + p0[nt][rr]);
        }
        // row el (wave-private) is fully written by this wave; read back
        // contiguously and store 16B/lane -> 64B coalesced segments per quad.
        const int e2 = t >> 2, q = t & 3;
        int spos = __float_as_int(sRS[e2 * 4 + 3]);
        ushort* row = psiA + (size_t)spos * 128;
#pragma unroll
        for (int j = 0; j < 4; ++j) {
            short8 vd = *(const short8*)&sACT[e2 * 136 + j * 32 + q * 8];
            __builtin_nontemporal_store(vd, (short8*)(row + j * 32 + q * 8));
        }
    }

    // psi_v via linearity: psiV[d] = s[d]*rs + T[d] + U[d] x rs
    // results staged bf16 in sACT (free after psi_a store), then wide NT store
    {
        short8 aY0 = *(const short8*)&sY0[arow * 72 + quad * 8];
        short8 aRL[3];
#pragma unroll
        for (int i = 0; i < 3; ++i)
            aRL[i] = *(const short8*)&sRELV[arow * 104 + i * 32 + quad * 8];

#pragma unroll
        for (int nt = 0; nt < 2; ++nt) {
            short8 b011 = *(const short8*)&W011b[(nt * 16 + r0) * 32 + quad * 8];
            short8 b111 = *(const short8*)&W111b[(nt * 16 + r0) * 32 + quad * 8];
            short8 b101 = *(const short8*)&W101b[(nt * 16 + r0) * 32 + quad * 8];
            f32x4 sA = __builtin_amdgcn_mfma_f32_16x16x32_bf16(
                aY0, b011, (f32x4){0.f, 0.f, 0.f, 0.f}, 0, 0, 0);
            f32x4 U[3], T[3];
#pragma unroll
            for (int i = 0; i < 3; ++i) {
                U[i] = __builtin_amdgcn_mfma_f32_16x16x32_bf16(
                    aRL[i], b111, (f32x4){0.f, 0.f, 0.f, 0.f}, 0, 0, 0);
                T[i] = __builtin_amdgcn_mfma_f32_16x16x32_bf16(
                    aRL[i], b101, (f32x4){0.f, 0.f, 0.f, 0.f}, 0, 0, 0);
            }
            int d = nt * 16 + r0;
#pragma unroll
            for (int rr = 0; rr < 4; ++rr) {
                int el = w * 16 + quad * 4 + rr;
                float4 rsv = *(const float4*)&sRS[el * 4];
                float s = sA[rr];
                float ux = U[0][rr], uy = U[1][rr], uz = U[2][rr];
                float ox = s * rsv.x + T[0][rr] + uy * rsv.z - uz * rsv.y;
                float oy = s * rsv.y + T[1][rr] + uz * rsv.x - ux * rsv.z;
                float oz = s * rsv.z + T[2][rr] + ux * rsv.y - uy * rsv.x;
                sACT[el * 136 + 0 * 32 + d] = f2bf(ox);
                sACT[el * 136 + 1 * 32 + d] = f2bf(oy);
                sACT[el * 136 + 2 * 32 + d] = f2bf(oz);
            }
        }
        const int e2 = t >> 2, q = t & 3;
        int spos = __float_as_int(sRS[e2 * 4 + 3]);
        ushort* row = psiV + (size_t)spos * 96;
#pragma unroll
        for (int j = 0; j < 3; ++j) {
            short8 vd = *(const short8*)&sACT[e2 * 136 + j * 32 + q * 8];
            __builtin_nontemporal_store(vd, (short8*)(row + j * 32 + q * 8));
        }
    }
}

// ---------------- segmented reduction (1 wave per node, src-sorted) ---------
__global__ __launch_bounds__(256) void reduce_kernel(
    const int* __restrict__ offsS, const ushort* __restrict__ psiA,
    const ushort* __restrict__ psiV,
    float* __restrict__ B_a, float* __restrict__ B_v)
{
    int n = blockIdx.x * 4 + (threadIdx.x >> 6);
    int lane = threadIdx.x & 63;
    if (n >= N_NODES) return;
    int p0 = offsS[n], p1 = offsS[n + 1];

    float a0 = 0.f, a1 = 0.f;
    for (int p = p0; p < p1; ++p) {
        unsigned int u = __builtin_nontemporal_load(
            (const unsigned int*)&psiA[(size_t)p * 128 + lane * 2]);
        a0 += bf2f((ushort)(u & 0xffff));
        a1 += bf2f((ushort)(u >> 16));
    }
    B_a[(size_t)n * 128 + lane * 2 + 0] = 0.1f * a0;
    B_a[(size_t)n * 128 + lane * 2 + 1] = 0.1f * a1;

    if (lane < 48) {
        float v0 = 0.f, v1 = 0.f;
        for (int p = p0; p < p1; ++p) {
            unsigned int u = __builtin_nontemporal_load(
                (const unsigned int*)&psiV[(size_t)p * 96 + lane * 2]);
            v0 += bf2f((ushort)(u & 0xffff));
            v1 += bf2f((ushort)(u >> 16));
        }
        int j0 = lane * 2, j1 = lane * 2 + 1;  // stored col = i*32+d; B_v idx = d*3+i
        B_v[(size_t)n * 96 + (j0 & 31) * 3 + (j0 >> 5)] = 0.1f * v0;
        B_v[(size_t)n * 96 + (j1 & 31) * 3 + (j1 >> 5)] = 0.1f * v1;
    }
}

extern "C" void kernel_launch(void* const* d_in, const int* in_sizes, int n_in,
                              void* d_out, int out_size, void* d_ws, size_t ws_size,
                              hipStream_t stream) {
    const float* x_a   = (const float*)d_in[0];
    const float* x_v   = (const float*)d_in[1];
    const float* r_ij  = (const float*)d_in[2];
    const int*   src   = (const int*)d_in[3];
    const int*   dst   = (const int*)d_in[4];
    const float* W_L0  = (const float*)d_in[5];
    const float* W_L1  = (const float*)d_in[6];
    const float* W_enc = (const float*)d_in[7];
    const float* b_enc = (const float*)d_in[8];
    const float* Wy000 = (const float*)d_in[9];
    const float* Wy110 = (const float*)d_in[10];
    const float* Wy011 = (const float*)d_in[11];
    const float* Wy101 = (const float*)d_in[12];
    const float* Wy111 = (const float*)d_in[13];
    const float* Wm1   = (const float*)d_in[14];
    const float* bm1   = (const float*)d_in[15];
    const float* Wm2   = (const float*)d_in[16];
    const float* bm2   = (const float*)d_in[17];
    const float* Wm3   = (const float*)d_in[18];

    float* out = (float*)d_out;
    float* B_a = out;
    float* B_v = out + (size_t)N_NODES * DIM_A;

    char* w = (char*)d_ws;
    float* LN     = (float*)w;  w += (size_t)N_NODES * 128 * 4;   // 25.6 MB
    int*   degS   = (int*)w;    w += (size_t)N_NODES * 4;
    int*   degD   = (int*)w;    w += (size_t)N_NODES * 4;
    int*   offsS  = (int*)w;    w += (size_t)(N_NODES + 16) * 4;
    int*   curS   = (int*)w;    w += (size_t)N_NODES * 4;
    int*   offsD  = (int*)w;    w += (size_t)(N_NODES + 16) * 4;
    int*   curD   = (int*)w;    w += (size_t)N_NODES * 4;
    int*   excl   = (int*)w;    w += (size_t)N_NODES * 4;
    int*   bsum   = (int*)w;    w += 64 * 4;
    int*   sposD  = (int*)w;    w += (size_t)N_EDGES * 4;
    float4* edgeD = (float4*)w; w += (size_t)N_EDGES * 16;
    ushort* W0b   = (ushort*)w; w += 128 * 64 * 2;
    ushort* Wm1b  = (ushort*)w; w += 128 * 128 * 2;
    ushort* Wm2b  = (ushort*)w; w += 128 * 128 * 2;
    ushort* Wm3b  = (ushort*)w; w += 128 * 128 * 2;
    ushort* W011b = (ushort*)w; w += 32 * 32 * 2;
    ushort* W101b = (ushort*)w; w += 32 * 32 * 2;
    ushort* W111b = (ushort*)w; w += 32 * 32 * 2;
    ushort* psiA  = (ushort*)w; w += (size_t)N_EDGES * 128 * 2;   // 128 MB
    ushort* psiV  = (ushort*)w; w += (size_t)N_EDGES * 96 * 2;    // 96 MB
    int*   srcPos = (int*)psiA;  // alias: consumed before psiA is written

    hipMemsetAsync(degS, 0, 2 * N_NODES * sizeof(int), stream);  // degS+degD adjacent

    convw_kernel<<<64, 256, 0, stream>>>(Wy000, Wy110, Wy011, Wy101, Wy111,
                                         Wm1, Wm2, Wm3,
                                         W0b, Wm1b, Wm2b, Wm3b, W011b, W101b, W111b);
    node_proj_kernel<<<(N_NODES + 7) / 8, 256, 0, stream>>>(x_a, x_v, W_L0, W_L1, LN);

    hist2_kernel<<<(N_EDGES + 255) / 256, 256, 0, stream>>>(src, dst, degS, degD);

    scan1_kernel<<<SCAN_B, 1024, 0, stream>>>(degS, excl, bsum);
    scan2_kernel<<<1, 64, 0, stream>>>(bsum);
    scan3_kernel<<<SCAN_B, 1024, 0, stream>>>(excl, bsum, offsS, curS);

    scan1_kernel<<<SCAN_B, 1024, 0, stream>>>(degD, excl, bsum);
    scan2_kernel<<<1, 64, 0, stream>>>(bsum);
    scan3_kernel<<<SCAN_B, 1024, 0, stream>>>(excl, bsum, offsD, curD);

    scatterS_kernel<<<(N_EDGES + 255) / 256, 256, 0, stream>>>(src, curS, srcPos);
    scatterD_kernel<<<(N_EDGES + 255) / 256, 256, 0, stream>>>(dst, r_ij, srcPos, curD,
                                                               edgeD, sposD);

    edge_mfma_kernel<<<(N_EDGES + EB - 1) / EB, 256, 0, stream>>>(
        edgeD, sposD, LN, W_enc, b_enc,
        W0b, Wm1b, Wm2b, Wm3b, W011b, W101b, W111b,
        bm1, bm2, psiA, psiV);

    reduce_kernel<<<(N_NODES + 3) / 4, 256, 0, stream>>>(offsS, psiA, psiV, B_a, B_v);
}

// Round 2
// 665.324 us; speedup vs baseline: 1.4548x; 1.4539x over previous
//
#include <hip/hip_runtime.h>
#include <hip/hip_bf16.h>

#define N_NODES 50000
#define N_EDGES 500000
#define DIM_A 128
#define DIM_V 32
#define CHAN 32
#define EB 64            // edges per block in edge kernel
#define SCAN_B 49        // ceil(50000/1024)

typedef __attribute__((ext_vector_type(8))) short short8;
typedef __attribute__((ext_vector_type(8))) unsigned short ushort8;
typedef __attribute__((ext_vector_type(4))) float f32x4;
typedef unsigned short ushort;

#define MFMA __builtin_amdgcn_mfma_f32_16x16x32_bf16

__device__ __forceinline__ ushort f2bf(float x) {
    __hip_bfloat16 h = __float2bfloat16(x);
    return *reinterpret_cast<ushort*>(&h);
}
__device__ __forceinline__ float bf2f(ushort u) {
    union { float f; unsigned int i; } v; v.i = ((unsigned int)u) << 16; return v.f;
}
__device__ __forceinline__ float leaky(float x) {
    return x >= 0.f ? x : 0.1f * x;
}

// ---------------- weight conversion: MFMA-fragment-packed layouts ----------
// Fragment packing: element W[o][c] (o = output col, c = K index) lives at
//   ushort idx = ((o>>4)*KB + (c>>5))*512 + ((c>>3)&3)*128 + (o&15)*8 + (c&7)
// so a wave's B-fragment (fixed nt=o>>4, kb=c>>5) is the contiguous 1KB chunk
//   frag_short8[ (nt*KB+kb)*64 + lane ]   (lane = quad*16 + r0)
__global__ __launch_bounds__(256) void convw_kernel(
    const float* __restrict__ Wy000, const float* __restrict__ Wy110,
    const float* __restrict__ Wy011, const float* __restrict__ Wy101,
    const float* __restrict__ Wy111,
    const float* __restrict__ Wm1, const float* __restrict__ Wm2,
    const float* __restrict__ Wm3,
    ushort* __restrict__ W0b, ushort* __restrict__ Wm1b,
    ushort* __restrict__ Wm2b, ushort* __restrict__ Wm3b,
    ushort* __restrict__ W011b, ushort* __restrict__ W101b,
    ushort* __restrict__ W111b)
{
    int g = blockIdx.x * 256 + threadIdx.x;
    if (g < 128 * 128) {          // [128][128] matrices, KB=4
        int o = g >> 7, c = g & 127;
        int pi = ((o >> 4) * 4 + (c >> 5)) * 512 + ((c >> 3) & 3) * 128
               + (o & 15) * 8 + (c & 7);
        Wm1b[pi] = f2bf(Wm1[g]);
        Wm2b[pi] = f2bf(Wm2[g]);
        Wm3b[pi] = f2bf(Wm3[g]);
    }
    if (g < 128 * 64) {           // W0cat [128][64], KB=2; c<32 Wy000 else Wy110
        int o = g >> 6, c = g & 63;
        float v = (c < 32) ? Wy000[o * 32 + c] : Wy110[o * 32 + (c - 32)];
        int pi = ((o >> 4) * 2 + (c >> 5)) * 512 + ((c >> 3) & 3) * 128
               + (o & 15) * 8 + (c & 7);
        W0b[pi] = f2bf(v);
    }
    if (g < 32 * 32) {            // [32][32] matrices, KB=1
        int o = g >> 5, c = g & 31;
        int pi = (o >> 4) * 512 + ((c >> 3) & 3) * 128 + (o & 15) * 8 + (c & 7);
        W011b[pi] = f2bf(Wy011[g]);
        W101b[pi] = f2bf(Wy101[g]);
        W111b[pi] = f2bf(Wy111[g]);
    }
}

// ---------------- node projection: LN[n][128] = [L0(32) | L1(96, c*3+i)] ----
__global__ __launch_bounds__(256) void node_proj_kernel(
    const float* __restrict__ x_a, const float* __restrict__ x_v,
    const float* __restrict__ W_L0, const float* __restrict__ W_L1,
    float* __restrict__ LN)
{
    int t = threadIdx.x;
    int n = blockIdx.x * 8 + (t >> 5);
    int c = t & 31;
    if (n >= N_NODES) return;

    const float4* xa = (const float4*)(x_a + (size_t)n * DIM_A);
    const float4* w0 = (const float4*)(W_L0 + c * DIM_A);
    float acc = 0.f;
#pragma unroll 8
    for (int k = 0; k < DIM_A / 4; ++k) {
        float4 x = xa[k]; float4 w = w0[k];
        acc += x.x * w.x + x.y * w.y + x.z * w.z + x.w * w.w;
    }
    LN[(size_t)n * 128 + c] = acc;

    const float* xv = x_v + (size_t)n * DIM_V * 3;
    const float* w1 = W_L1 + c * DIM_V;
    float a0 = 0.f, a1 = 0.f, a2 = 0.f;
#pragma unroll 8
    for (int d = 0; d < DIM_V; ++d) {
        float w = w1[d];
        a0 += xv[d * 3 + 0] * w;
        a1 += xv[d * 3 + 1] * w;
        a2 += xv[d * 3 + 2] * w;
    }
    float* o = LN + (size_t)n * 128 + 32 + c * 3;
    o[0] = a0; o[1] = a1; o[2] = a2;
}

// ---------------- dual histogram ----------------
__global__ __launch_bounds__(256) void hist2_kernel(
    const int* __restrict__ src, const int* __restrict__ dst,
    int* __restrict__ degS, int* __restrict__ degD)
{
    int i = blockIdx.x * 256 + threadIdx.x;
    if (i < N_EDGES) {
        atomicAdd(&degS[src[i]], 1);
        atomicAdd(&degD[dst[i]], 1);
    }
}

// ---------------- 3-phase multi-block exclusive scan ----------------
__global__ __launch_bounds__(1024) void scan1_kernel(const int* __restrict__ deg,
                                                     int* __restrict__ excl,
                                                     int* __restrict__ bsum)
{
    __shared__ int buf[1024];
    int t = threadIdx.x;
    int i = blockIdx.x * 1024 + t;
    int v = (i < N_NODES) ? deg[i] : 0;
    buf[t] = v;
    __syncthreads();
    for (int off = 1; off < 1024; off <<= 1) {
        int x = (t >= off) ? buf[t - off] : 0;
        __syncthreads();
        buf[t] += x;
        __syncthreads();
    }
    if (i < N_NODES) excl[i] = buf[t] - v;
    if (t == 1023) bsum[blockIdx.x] = buf[1023];
}

__global__ void scan2_kernel(int* __restrict__ bsum)
{
    if (threadIdx.x == 0) {
        int s = 0;
        for (int k = 0; k < SCAN_B; ++k) { int x = bsum[k]; bsum[k] = s; s += x; }
    }
}

__global__ __launch_bounds__(1024) void scan3_kernel(const int* __restrict__ excl,
                                                     const int* __restrict__ bsum,
                                                     int* __restrict__ offs,
                                                     int* __restrict__ cursor)
{
    int t = threadIdx.x;
    int i = blockIdx.x * 1024 + t;
    if (i < N_NODES) {
        int o = excl[i] + bsum[blockIdx.x];
        offs[i] = o;
        cursor[i] = o;
    }
    if (i == 0) offs[N_NODES] = N_EDGES;
}

// ---------------- scatter: src slots, then dst-order packed edge records ----
__global__ __launch_bounds__(256) void scatterS_kernel(const int* __restrict__ src,
                                                       int* __restrict__ curS,
                                                       int* __restrict__ srcPos)
{
    int i = blockIdx.x * 256 + threadIdx.x;
    if (i < N_EDGES) srcPos[i] = atomicAdd(&curS[src[i]], 1);
}

__global__ __launch_bounds__(256) void scatterD_kernel(
    const int* __restrict__ dst, const float* __restrict__ r_ij,
    const int* __restrict__ srcPos, int* __restrict__ curD,
    float4* __restrict__ edgeD, int* __restrict__ sposD)
{
    int i = blockIdx.x * 256 + threadIdx.x;
    if (i < N_EDGES) {
        int d = dst[i];
        int p = atomicAdd(&curD[d], 1);
        edgeD[p] = make_float4(r_ij[i * 3 + 0], r_ij[i * 3 + 1], r_ij[i * 3 + 2],
                               __int_as_float(d));
        sposD[p] = srcPos[i];
    }
}

// ---------------- MFMA edge kernel (col-tiled MLP, dst-order, 4 blocks/CU) --
// v3: the 512us stall was serial weight-load latency (~130 VMEM x ~300cyc L2,
// VGPR=56 -> no loads in flight). Fix: (a) fragment-packed weights => one
// contiguous 1KB load per B-fragment, hoistable; (b) MLP layers col-tiled
// across the 4 waves (each wave: 32 cols x 64 edges) => 4x fewer weight loads,
// all hoisted before the MFMA chain; barriers carry activations cross-wave.
// LDS exactly 40960 B: sY0 9216 + sRELV 13312 + sACT 17408 + sRS 1024.
__global__ __launch_bounds__(256, 4) void edge_mfma_kernel(
    const float4* __restrict__ edgeD, const int* __restrict__ sposD,
    const float* __restrict__ LN,
    const float* __restrict__ W_enc, const float* __restrict__ b_enc,
    const ushort* __restrict__ W0b, const ushort* __restrict__ Wm1b,
    const ushort* __restrict__ Wm2b, const ushort* __restrict__ Wm3b,
    const ushort* __restrict__ W011b, const ushort* __restrict__ W101b,
    const ushort* __restrict__ W111b,
    const float* __restrict__ bm1, const float* __restrict__ bm2,
    ushort* __restrict__ psiA, ushort* __restrict__ psiV)
{
    __shared__ __align__(16) ushort sY0[64 * 72];     // [e][72]: 0..31 y000, 32..63 y110
    __shared__ __align__(16) ushort sRELV[64 * 104];  // [e][104]: i*32+c = re*lv_i
    __shared__ __align__(16) ushort sACT[64 * 136];   // [e][136] activations
    __shared__ __align__(16) float sRS[64 * 4];       // [e]: rsx,rsy,rsz,spos-bits

    const int t = threadIdx.x;
    const int e0 = blockIdx.x * EB;

    // ---- phase 1: per-edge features -> LDS (wave-row partitioned) ----
    {
        const int e = t >> 2;          // wave w owns e in [16w,16w+16)
        const int p = t & 3;           // 8 channels each
        const int qe = min(e0 + e, N_EDGES - 1);
        f32x4 edv = __builtin_nontemporal_load((const f32x4*)edgeD + qe);
        int spos = __builtin_nontemporal_load(sposD + qe);
        float rx = edv[0], ry = edv[1], rz = edv[2];
        int dn = __float_as_int(edv[3]);
        float r = sqrtf(rx * rx + ry * ry + rz * rz);

        float rad[8];
#pragma unroll
        for (int k = 0; k < 8; ++k) {
            float d = (r - (5.0f / 7.0f) * (float)k) * 1.6f;
            rad[k] = expf(-d * d);
        }
        float n14 = 1.4f * r;
        float tt = tanhf(n14) / fmaxf(n14, 1e-6f);
        float rsx = 1.4f * rx * tt, rsy = 1.4f * ry * tt, rsz = 1.4f * rz * tt;
        if (p == 0) {
            *(float4*)&sRS[e * 4] = make_float4(rsx, rsy, rsz, __int_as_float(spos));
        }

        float la[8];
        {
            const float4* lap = (const float4*)(LN + (size_t)dn * 128 + p * 8);
            float4 A = lap[0], B = lap[1];
            la[0] = A.x; la[1] = A.y; la[2] = A.z; la[3] = A.w;
            la[4] = B.x; la[5] = B.y; la[6] = B.z; la[7] = B.w;
        }
        float lv[24];
        {
            const float4* lvp = (const float4*)(LN + (size_t)dn * 128 + 32 + p * 24);
#pragma unroll
            for (int q = 0; q < 6; ++q) {
                float4 v = lvp[q];
                lv[q * 4 + 0] = v.x; lv[q * 4 + 1] = v.y;
                lv[q * 4 + 2] = v.z; lv[q * 4 + 3] = v.w;
            }
        }

        ushort8 u000, u110, url[3];
#pragma unroll
        for (int j = 0; j < 8; ++j) {
            int c = p * 8 + j;
            float re = b_enc[c];
#pragma unroll
            for (int k = 0; k < 8; ++k) re += rad[k] * W_enc[c * 8 + k];
            float lvx = lv[j * 3 + 0], lvy = lv[j * 3 + 1], lvz = lv[j * 3 + 2];
            float dotv = lvx * rsx + lvy * rsy + lvz * rsz;
            u000[j] = f2bf(la[j] * re);
            u110[j] = f2bf(re * dotv);
            url[0][j] = f2bf(re * lvx);
            url[1][j] = f2bf(re * lvy);
            url[2][j] = f2bf(re * lvz);
        }
        *(ushort8*)&sY0[e * 72 + p * 8]      = u000;
        *(ushort8*)&sY0[e * 72 + 32 + p * 8] = u110;
#pragma unroll
        for (int i = 0; i < 3; ++i)
            *(ushort8*)&sRELV[e * 104 + i * 32 + p * 8] = url[i];
    }

    __syncthreads();                       // B1: features visible block-wide

    const int lane = t & 63;
    const int w = t >> 6;
    const int r0 = lane & 15;
    const int quad = lane >> 4;
    const int colw = w * 32;               // this wave's output-col base

    const short8* W0f   = (const short8*)W0b;
    const short8* Wm1f  = (const short8*)Wm1b;
    const short8* Wm2f  = (const short8*)Wm2b;
    const short8* Wm3f  = (const short8*)Wm3b;
    const short8* W011f = (const short8*)W011b;
    const short8* W101f = (const short8*)W101b;
    const short8* W111f = (const short8*)W111b;

    // ---- psi0 = Y0 @ W0cat^T (K=64), col-tiled: cols [colw, colw+32) ----
    f32x4 p0[4][2];
#pragma unroll
    for (int nt2 = 0; nt2 < 2; ++nt2) {
        short8 Bk0 = W0f[((w * 2 + nt2) * 2 + 0) * 64 + lane];
        short8 Bk1 = W0f[((w * 2 + nt2) * 2 + 1) * 64 + lane];
#pragma unroll
        for (int g = 0; g < 4; ++g) {
            short8 a0 = *(const short8*)&sY0[(g * 16 + r0) * 72 + quad * 8];
            short8 a1 = *(const short8*)&sY0[(g * 16 + r0) * 72 + 32 + quad * 8];
            f32x4 acc = {0.f, 0.f, 0.f, 0.f};
            acc = MFMA(a0, Bk0, acc, 0, 0, 0);
            acc = MFMA(a1, Bk1, acc, 0, 0, 0);
            p0[g][nt2] = acc;
#pragma unroll
            for (int rr = 0; rr < 4; ++rr)
                sACT[(g * 16 + quad * 4 + rr) * 136 + colw + nt2 * 16 + r0] =
                    f2bf(acc[rr]);
        }
    }
    __syncthreads();                       // B2: psi0 activations ready

    // ---- h1 = leaky(act @ Wm1^T + bm1): compute, barrier, write, barrier ----
    f32x4 hv[2][4];
#pragma unroll
    for (int nt2 = 0; nt2 < 2; ++nt2) {
        short8 Bw[4];
#pragma unroll
        for (int kb = 0; kb < 4; ++kb)
            Bw[kb] = Wm1f[((w * 2 + nt2) * 4 + kb) * 64 + lane];
        float bv = bm1[colw + nt2 * 16 + r0];
#pragma unroll
        for (int g = 0; g < 4; ++g) {
            f32x4 acc = {bv, bv, bv, bv};
#pragma unroll
            for (int kb = 0; kb < 4; ++kb) {
                short8 a = *(const short8*)&sACT[(g * 16 + r0) * 136 + kb * 32 + quad * 8];
                acc = MFMA(a, Bw[kb], acc, 0, 0, 0);
            }
#pragma unroll
            for (int rr = 0; rr < 4; ++rr) acc[rr] = leaky(acc[rr]);
            hv[nt2][g] = acc;
        }
    }
    __syncthreads();                       // B3a: psi0 reads complete
#pragma unroll
    for (int nt2 = 0; nt2 < 2; ++nt2)
#pragma unroll
        for (int g = 0; g < 4; ++g)
#pragma unroll
            for (int rr = 0; rr < 4; ++rr)
                sACT[(g * 16 + quad * 4 + rr) * 136 + colw + nt2 * 16 + r0] =
                    f2bf(hv[nt2][g][rr]);
    __syncthreads();                       // B3b: h1 ready

    // ---- h2 = leaky(act @ Wm2^T + bm2) ----
#pragma unroll
    for (int nt2 = 0; nt2 < 2; ++nt2) {
        short8 Bw[4];
#pragma unroll
        for (int kb = 0; kb < 4; ++kb)
            Bw[kb] = Wm2f[((w * 2 + nt2) * 4 + kb) * 64 + lane];
        float bv = bm2[colw + nt2 * 16 + r0];
#pragma unroll
        for (int g = 0; g < 4; ++g) {
            f32x4 acc = {bv, bv, bv, bv};
#pragma unroll
            for (int kb = 0; kb < 4; ++kb) {
                short8 a = *(const short8*)&sACT[(g * 16 + r0) * 136 + kb * 32 + quad * 8];
                acc = MFMA(a, Bw[kb], acc, 0, 0, 0);
            }
#pragma unroll
            for (int rr = 0; rr < 4; ++rr) acc[rr] = leaky(acc[rr]);
            hv[nt2][g] = acc;
        }
    }
    __syncthreads();                       // B4a: h1 reads complete
#pragma unroll
    for (int nt2 = 0; nt2 < 2; ++nt2)
#pragma unroll
        for (int g = 0; g < 4; ++g)
#pragma unroll
            for (int rr = 0; rr < 4; ++rr)
                sACT[(g * 16 + quad * 4 + rr) * 136 + colw + nt2 * 16 + r0] =
                    f2bf(hv[nt2][g][rr]);
    __syncthreads();                       // B4b: h2 ready

    // ---- psi_a = psi0 + h2 @ Wm3^T: direct scattered stores (no sACT write) --
#pragma unroll
    for (int nt2 = 0; nt2 < 2; ++nt2) {
        short8 Bw[4];
#pragma unroll
        for (int kb = 0; kb < 4; ++kb)
            Bw[kb] = Wm3f[((w * 2 + nt2) * 4 + kb) * 64 + lane];
#pragma unroll
        for (int g = 0; g < 4; ++g) {
            f32x4 acc = {0.f, 0.f, 0.f, 0.f};
#pragma unroll
            for (int kb = 0; kb < 4; ++kb) {
                short8 a = *(const short8*)&sACT[(g * 16 + r0) * 136 + kb * 32 + quad * 8];
                acc = MFMA(a, Bw[kb], acc, 0, 0, 0);
            }
#pragma unroll
            for (int rr = 0; rr < 4; ++rr) {
                int el = g * 16 + quad * 4 + rr;
                int spos = __float_as_int(sRS[el * 4 + 3]);
                psiA[(size_t)spos * 128 + colw + nt2 * 16 + r0] =
                    f2bf(acc[rr] + p0[g][nt2][rr]);
            }
        }
    }

    // ---- psi_v (row-tiled, wave-local rows): psiV[d] = s[d]*rs + T[d] + U[d] x rs
    {
        const int arow = w * 16 + r0;
        short8 aY0 = *(const short8*)&sY0[arow * 72 + quad * 8];
        short8 aRL[3];
#pragma unroll
        for (int i = 0; i < 3; ++i)
            aRL[i] = *(const short8*)&sRELV[arow * 104 + i * 32 + quad * 8];

#pragma unroll
        for (int nt = 0; nt < 2; ++nt) {
            short8 b011 = W011f[nt * 64 + lane];
            short8 b111 = W111f[nt * 64 + lane];
            short8 b101 = W101f[nt * 64 + lane];
            f32x4 sA = MFMA(aY0, b011, (f32x4){0.f, 0.f, 0.f, 0.f}, 0, 0, 0);
            f32x4 U[3], T[3];
#pragma unroll
            for (int i = 0; i < 3; ++i) {
                U[i] = MFMA(aRL[i], b111, (f32x4){0.f, 0.f, 0.f, 0.f}, 0, 0, 0);
                T[i] = MFMA(aRL[i], b101, (f32x4){0.f, 0.f, 0.f, 0.f}, 0, 0, 0);
            }
            int d = nt * 16 + r0;
#pragma unroll
            for (int rr = 0; rr < 4; ++rr) {
                int el = w * 16 + quad * 4 + rr;
                float4 rsv = *(const float4*)&sRS[el * 4];
                int spos = __float_as_int(rsv.w);
                float s = sA[rr];
                float ux = U[0][rr], uy = U[1][rr], uz = U[2][rr];
                float ox = s * rsv.x + T[0][rr] + uy * rsv.z - uz * rsv.y;
                float oy = s * rsv.y + T[1][rr] + uz * rsv.x - ux * rsv.z;
                float oz = s * rsv.z + T[2][rr] + ux * rsv.y - uy * rsv.x;
                ushort* row = psiV + (size_t)spos * 96;
                row[0 * 32 + d] = f2bf(ox);
                row[1 * 32 + d] = f2bf(oy);
                row[2 * 32 + d] = f2bf(oz);
            }
        }
    }
}

// ---------------- segmented reduction (1 wave per node, src-sorted) ---------
__global__ __launch_bounds__(256) void reduce_kernel(
    const int* __restrict__ offsS, const ushort* __restrict__ psiA,
    const ushort* __restrict__ psiV,
    float* __restrict__ B_a, float* __restrict__ B_v)
{
    int n = blockIdx.x * 4 + (threadIdx.x >> 6);
    int lane = threadIdx.x & 63;
    if (n >= N_NODES) return;
    int p0 = offsS[n], p1 = offsS[n + 1];

    float a0 = 0.f, a1 = 0.f;
    for (int p = p0; p < p1; ++p) {
        unsigned int u = __builtin_nontemporal_load(
            (const unsigned int*)&psiA[(size_t)p * 128 + lane * 2]);
        a0 += bf2f((ushort)(u & 0xffff));
        a1 += bf2f((ushort)(u >> 16));
    }
    B_a[(size_t)n * 128 + lane * 2 + 0] = 0.1f * a0;
    B_a[(size_t)n * 128 + lane * 2 + 1] = 0.1f * a1;

    if (lane < 48) {
        float v0 = 0.f, v1 = 0.f;
        for (int p = p0; p < p1; ++p) {
            unsigned int u = __builtin_nontemporal_load(
                (const unsigned int*)&psiV[(size_t)p * 96 + lane * 2]);
            v0 += bf2f((ushort)(u & 0xffff));
            v1 += bf2f((ushort)(u >> 16));
        }
        int j0 = lane * 2, j1 = lane * 2 + 1;  // stored col = i*32+d; B_v idx = d*3+i
        B_v[(size_t)n * 96 + (j0 & 31) * 3 + (j0 >> 5)] = 0.1f * v0;
        B_v[(size_t)n * 96 + (j1 & 31) * 3 + (j1 >> 5)] = 0.1f * v1;
    }
}

extern "C" void kernel_launch(void* const* d_in, const int* in_sizes, int n_in,
                              void* d_out, int out_size, void* d_ws, size_t ws_size,
                              hipStream_t stream) {
    const float* x_a   = (const float*)d_in[0];
    const float* x_v   = (const float*)d_in[1];
    const float* r_ij  = (const float*)d_in[2];
    const int*   src   = (const int*)d_in[3];
    const int*   dst   = (const int*)d_in[4];
    const float* W_L0  = (const float*)d_in[5];
    const float* W_L1  = (const float*)d_in[6];
    const float* W_enc = (const float*)d_in[7];
    const float* b_enc = (const float*)d_in[8];
    const float* Wy000 = (const float*)d_in[9];
    const float* Wy110 = (const float*)d_in[10];
    const float* Wy011 = (const float*)d_in[11];
    const float* Wy101 = (const float*)d_in[12];
    const float* Wy111 = (const float*)d_in[13];
    const float* Wm1   = (const float*)d_in[14];
    const float* bm1   = (const float*)d_in[15];
    const float* Wm2   = (const float*)d_in[16];
    const float* bm2   = (const float*)d_in[17];
    const float* Wm3   = (const float*)d_in[18];

    float* out = (float*)d_out;
    float* B_a = out;
    float* B_v = out + (size_t)N_NODES * DIM_A;

    char* w = (char*)d_ws;
    float* LN     = (float*)w;  w += (size_t)N_NODES * 128 * 4;   // 25.6 MB
    int*   degS   = (int*)w;    w += (size_t)N_NODES * 4;
    int*   degD   = (int*)w;    w += (size_t)N_NODES * 4;
    int*   offsS  = (int*)w;    w += (size_t)(N_NODES + 16) * 4;
    int*   curS   = (int*)w;    w += (size_t)N_NODES * 4;
    int*   offsD  = (int*)w;    w += (size_t)(N_NODES + 16) * 4;
    int*   curD   = (int*)w;    w += (size_t)N_NODES * 4;
    int*   excl   = (int*)w;    w += (size_t)N_NODES * 4;
    int*   bsum   = (int*)w;    w += 64 * 4;
    int*   sposD  = (int*)w;    w += (size_t)N_EDGES * 4;
    float4* edgeD = (float4*)w; w += (size_t)N_EDGES * 16;
    ushort* W0b   = (ushort*)w; w += 128 * 64 * 2;
    ushort* Wm1b  = (ushort*)w; w += 128 * 128 * 2;
    ushort* Wm2b  = (ushort*)w; w += 128 * 128 * 2;
    ushort* Wm3b  = (ushort*)w; w += 128 * 128 * 2;
    ushort* W011b = (ushort*)w; w += 32 * 32 * 2;
    ushort* W101b = (ushort*)w; w += 32 * 32 * 2;
    ushort* W111b = (ushort*)w; w += 32 * 32 * 2;
    ushort* psiA  = (ushort*)w; w += (size_t)N_EDGES * 128 * 2;   // 128 MB
    ushort* psiV  = (ushort*)w; w += (size_t)N_EDGES * 96 * 2;    // 96 MB
    int*   srcPos = (int*)psiA;  // alias: consumed before psiA is written

    hipMemsetAsync(degS, 0, 2 * N_NODES * sizeof(int), stream);  // degS+degD adjacent

    convw_kernel<<<64, 256, 0, stream>>>(Wy000, Wy110, Wy011, Wy101, Wy111,
                                         Wm1, Wm2, Wm3,
                                         W0b, Wm1b, Wm2b, Wm3b, W011b, W101b, W111b);
    node_proj_kernel<<<(N_NODES + 7) / 8, 256, 0, stream>>>(x_a, x_v, W_L0, W_L1, LN);

    hist2_kernel<<<(N_EDGES + 255) / 256, 256, 0, stream>>>(src, dst, degS, degD);

    scan1_kernel<<<SCAN_B, 1024, 0, stream>>>(degS, excl, bsum);
    scan2_kernel<<<1, 64, 0, stream>>>(bsum);
    scan3_kernel<<<SCAN_B, 1024, 0, stream>>>(excl, bsum, offsS, curS);

    scan1_kernel<<<SCAN_B, 1024, 0, stream>>>(degD, excl, bsum);
    scan2_kernel<<<1, 64, 0, stream>>>(bsum);
    scan3_kernel<<<SCAN_B, 1024, 0, stream>>>(excl, bsum, offsD, curD);

    scatterS_kernel<<<(N_EDGES + 255) / 256, 256, 0, stream>>>(src, curS, srcPos);
    scatterD_kernel<<<(N_EDGES + 255) / 256, 256, 0, stream>>>(dst, r_ij, srcPos, curD,
                                                               edgeD, sposD);

    edge_mfma_kernel<<<(N_EDGES + EB - 1) / EB, 256, 0, stream>>>(
        edgeD, sposD, LN, W_enc, b_enc,
        W0b, Wm1b, Wm2b, Wm3b, W011b, W101b, W111b,
        bm1, bm2, psiA, psiV);

    reduce_kernel<<<(N_NODES + 3) / 4, 256, 0, stream>>>(offsS, psiA, psiV, B_a, B_v);
}

// Round 3
// 517.750 us; speedup vs baseline: 1.8694x; 1.2850x over previous
//
#include <hip/hip_runtime.h>
#include <hip/hip_bf16.h>

#define N_NODES 50000
#define N_EDGES 500000
#define DIM_A 128
#define DIM_V 32
#define CHAN 32
#define EB 64            // edges per block in edge kernel
#define SCAN_B 49        // ceil(50000/1024)

typedef __attribute__((ext_vector_type(8))) short short8;
typedef __attribute__((ext_vector_type(8))) unsigned short ushort8;
typedef __attribute__((ext_vector_type(4))) float f32x4;
typedef unsigned short ushort;

#define MFMA __builtin_amdgcn_mfma_f32_16x16x32_bf16

__device__ __forceinline__ ushort f2bf(float x) {
    __hip_bfloat16 h = __float2bfloat16(x);
    return *reinterpret_cast<ushort*>(&h);
}
__device__ __forceinline__ float bf2f(ushort u) {
    union { float f; unsigned int i; } v; v.i = ((unsigned int)u) << 16; return v.f;
}
__device__ __forceinline__ float leaky(float x) {
    return x >= 0.f ? x : 0.1f * x;
}

// ---------------- weight conversion: MFMA-fragment-packed layouts ----------
// Fragment packing: element W[o][c] (o = output col, c = K index) lives at
//   ushort idx = ((o>>4)*KB + (c>>5))*512 + ((c>>3)&3)*128 + (o&15)*8 + (c&7)
// so a wave's B-fragment (fixed nt=o>>4, kb=c>>5) is the contiguous 1KB chunk
//   frag_short8[ (nt*KB+kb)*64 + lane ]   (lane = quad*16 + r0)
__global__ __launch_bounds__(256) void convw_kernel(
    const float* __restrict__ Wy000, const float* __restrict__ Wy110,
    const float* __restrict__ Wy011, const float* __restrict__ Wy101,
    const float* __restrict__ Wy111,
    const float* __restrict__ Wm1, const float* __restrict__ Wm2,
    const float* __restrict__ Wm3,
    ushort* __restrict__ W0b, ushort* __restrict__ Wm1b,
    ushort* __restrict__ Wm2b, ushort* __restrict__ Wm3b,
    ushort* __restrict__ W011b, ushort* __restrict__ W101b,
    ushort* __restrict__ W111b)
{
    int g = blockIdx.x * 256 + threadIdx.x;
    if (g < 128 * 128) {          // [128][128] matrices, KB=4
        int o = g >> 7, c = g & 127;
        int pi = ((o >> 4) * 4 + (c >> 5)) * 512 + ((c >> 3) & 3) * 128
               + (o & 15) * 8 + (c & 7);
        Wm1b[pi] = f2bf(Wm1[g]);
        Wm2b[pi] = f2bf(Wm2[g]);
        Wm3b[pi] = f2bf(Wm3[g]);
    }
    if (g < 128 * 64) {           // W0cat [128][64], KB=2; c<32 Wy000 else Wy110
        int o = g >> 6, c = g & 63;
        float v = (c < 32) ? Wy000[o * 32 + c] : Wy110[o * 32 + (c - 32)];
        int pi = ((o >> 4) * 2 + (c >> 5)) * 512 + ((c >> 3) & 3) * 128
               + (o & 15) * 8 + (c & 7);
        W0b[pi] = f2bf(v);
    }
    if (g < 32 * 32) {            // [32][32] matrices, KB=1
        int o = g >> 5, c = g & 31;
        int pi = (o >> 4) * 512 + ((c >> 3) & 3) * 128 + (o & 15) * 8 + (c & 7);
        W011b[pi] = f2bf(Wy011[g]);
        W101b[pi] = f2bf(Wy101[g]);
        W111b[pi] = f2bf(Wy111[g]);
    }
}

// ---------------- node projection: LN[n][128] = [L0(32) | L1(96, c*3+i)] ----
__global__ __launch_bounds__(256) void node_proj_kernel(
    const float* __restrict__ x_a, const float* __restrict__ x_v,
    const float* __restrict__ W_L0, const float* __restrict__ W_L1,
    float* __restrict__ LN)
{
    int t = threadIdx.x;
    int n = blockIdx.x * 8 + (t >> 5);
    int c = t & 31;
    if (n >= N_NODES) return;

    const float4* xa = (const float4*)(x_a + (size_t)n * DIM_A);
    const float4* w0 = (const float4*)(W_L0 + c * DIM_A);
    float acc = 0.f;
#pragma unroll 8
    for (int k = 0; k < DIM_A / 4; ++k) {
        float4 x = xa[k]; float4 w = w0[k];
        acc += x.x * w.x + x.y * w.y + x.z * w.z + x.w * w.w;
    }
    LN[(size_t)n * 128 + c] = acc;

    const float* xv = x_v + (size_t)n * DIM_V * 3;
    const float* w1 = W_L1 + c * DIM_V;
    float a0 = 0.f, a1 = 0.f, a2 = 0.f;
#pragma unroll 8
    for (int d = 0; d < DIM_V; ++d) {
        float w = w1[d];
        a0 += xv[d * 3 + 0] * w;
        a1 += xv[d * 3 + 1] * w;
        a2 += xv[d * 3 + 2] * w;
    }
    float* o = LN + (size_t)n * 128 + 32 + c * 3;
    o[0] = a0; o[1] = a1; o[2] = a2;
}

// ---------------- src histogram ----------------
__global__ __launch_bounds__(256) void hist_kernel(
    const int* __restrict__ src, int* __restrict__ degS)
{
    int i = blockIdx.x * 256 + threadIdx.x;
    if (i < N_EDGES) atomicAdd(&degS[src[i]], 1);
}

// ---------------- 3-phase multi-block exclusive scan ----------------
__global__ __launch_bounds__(1024) void scan1_kernel(const int* __restrict__ deg,
                                                     int* __restrict__ excl,
                                                     int* __restrict__ bsum)
{
    __shared__ int buf[1024];
    int t = threadIdx.x;
    int i = blockIdx.x * 1024 + t;
    int v = (i < N_NODES) ? deg[i] : 0;
    buf[t] = v;
    __syncthreads();
    for (int off = 1; off < 1024; off <<= 1) {
        int x = (t >= off) ? buf[t - off] : 0;
        __syncthreads();
        buf[t] += x;
        __syncthreads();
    }
    if (i < N_NODES) excl[i] = buf[t] - v;
    if (t == 1023) bsum[blockIdx.x] = buf[1023];
}

__global__ void scan2_kernel(int* __restrict__ bsum)
{
    if (threadIdx.x == 0) {
        int s = 0;
        for (int k = 0; k < SCAN_B; ++k) { int x = bsum[k]; bsum[k] = s; s += x; }
    }
}

__global__ __launch_bounds__(1024) void scan3_kernel(const int* __restrict__ excl,
                                                     const int* __restrict__ bsum,
                                                     int* __restrict__ offs,
                                                     int* __restrict__ cursor)
{
    int t = threadIdx.x;
    int i = blockIdx.x * 1024 + t;
    if (i < N_NODES) {
        int o = excl[i] + bsum[blockIdx.x];
        offs[i] = o;
        cursor[i] = o;
    }
    if (i == 0) offs[N_NODES] = N_EDGES;
}

// ---------------- scatter: build src-sorted packed edge records -------------
__global__ __launch_bounds__(256) void scatter_kernel(
    const int* __restrict__ src, const int* __restrict__ dst,
    const float* __restrict__ r_ij, int* __restrict__ curS,
    float4* __restrict__ edgeS, int* __restrict__ srcIdS)
{
    int i = blockIdx.x * 256 + threadIdx.x;
    if (i < N_EDGES) {
        int s = src[i];
        int p = atomicAdd(&curS[s], 1);
        edgeS[p] = make_float4(r_ij[i * 3 + 0], r_ij[i * 3 + 1], r_ij[i * 3 + 2],
                               __int_as_float(dst[i]));
        srcIdS[p] = s;
    }
}

// ---------------- MFMA edge kernel, fused segmented reduction ---------------
// v4: edges src-sorted; psi_a stays in sACT, psi_v lands in sRELV (free after
// its MFMA inputs are consumed); 224 threads do an in-LDS segmented sum over
// the block's 64 edges; interior runs -> plain store, block-boundary runs ->
// atomicAdd. Eliminates the 224MB psiA/psiV intermediate (+RMW inflation),
// reduce_kernel, scatterS, and one scan chain.
// LDS exactly 40960 B: sY0 9216 + sRELV 13312 + sACT 17408 + sRS 1024.
__global__ __launch_bounds__(256, 4) void edge_mfma_kernel(
    const float4* __restrict__ edgeS, const int* __restrict__ srcIdS,
    const float* __restrict__ LN,
    const float* __restrict__ W_enc, const float* __restrict__ b_enc,
    const ushort* __restrict__ W0b, const ushort* __restrict__ Wm1b,
    const ushort* __restrict__ Wm2b, const ushort* __restrict__ Wm3b,
    const ushort* __restrict__ W011b, const ushort* __restrict__ W101b,
    const ushort* __restrict__ W111b,
    const float* __restrict__ bm1, const float* __restrict__ bm2,
    float* __restrict__ B_a, float* __restrict__ B_v)
{
    __shared__ __align__(16) ushort sY0[64 * 72];     // [e][72]: 0..31 y000, 32..63 y110
    __shared__ __align__(16) ushort sRELV[64 * 104];  // [e]: in: re*lv_i; out: psi_v
    __shared__ __align__(16) ushort sACT[64 * 136];   // [e][136] act / final psi_a
    __shared__ __align__(16) float sRS[64 * 4];       // [e]: rsx,rsy,rsz,src-id-bits

    const int t = threadIdx.x;
    const int e0 = blockIdx.x * EB;

    // ---- phase 1: per-edge features -> LDS (wave-row partitioned) ----
    {
        const int e = t >> 2;          // wave w owns e in [16w,16w+16)
        const int p = t & 3;           // 8 channels each
        const int qe = min(e0 + e, N_EDGES - 1);
        f32x4 edv = __builtin_nontemporal_load((const f32x4*)edgeS + qe);
        int sid = __builtin_nontemporal_load(srcIdS + qe);
        float rx = edv[0], ry = edv[1], rz = edv[2];
        int dn = __float_as_int(edv[3]);
        float r = sqrtf(rx * rx + ry * ry + rz * rz);

        float rad[8];
#pragma unroll
        for (int k = 0; k < 8; ++k) {
            float d = (r - (5.0f / 7.0f) * (float)k) * 1.6f;
            rad[k] = expf(-d * d);
        }
        float n14 = 1.4f * r;
        float tt = tanhf(n14) / fmaxf(n14, 1e-6f);
        float rsx = 1.4f * rx * tt, rsy = 1.4f * ry * tt, rsz = 1.4f * rz * tt;
        if (p == 0) {
            *(float4*)&sRS[e * 4] = make_float4(rsx, rsy, rsz, __int_as_float(sid));
        }

        float la[8];
        {
            const float4* lap = (const float4*)(LN + (size_t)dn * 128 + p * 8);
            float4 A = lap[0], B = lap[1];
            la[0] = A.x; la[1] = A.y; la[2] = A.z; la[3] = A.w;
            la[4] = B.x; la[5] = B.y; la[6] = B.z; la[7] = B.w;
        }
        float lv[24];
        {
            const float4* lvp = (const float4*)(LN + (size_t)dn * 128 + 32 + p * 24);
#pragma unroll
            for (int q = 0; q < 6; ++q) {
                float4 v = lvp[q];
                lv[q * 4 + 0] = v.x; lv[q * 4 + 1] = v.y;
                lv[q * 4 + 2] = v.z; lv[q * 4 + 3] = v.w;
            }
        }

        ushort8 u000, u110, url[3];
#pragma unroll
        for (int j = 0; j < 8; ++j) {
            int c = p * 8 + j;
            float re = b_enc[c];
#pragma unroll
            for (int k = 0; k < 8; ++k) re += rad[k] * W_enc[c * 8 + k];
            float lvx = lv[j * 3 + 0], lvy = lv[j * 3 + 1], lvz = lv[j * 3 + 2];
            float dotv = lvx * rsx + lvy * rsy + lvz * rsz;
            u000[j] = f2bf(la[j] * re);
            u110[j] = f2bf(re * dotv);
            url[0][j] = f2bf(re * lvx);
            url[1][j] = f2bf(re * lvy);
            url[2][j] = f2bf(re * lvz);
        }
        *(ushort8*)&sY0[e * 72 + p * 8]      = u000;
        *(ushort8*)&sY0[e * 72 + 32 + p * 8] = u110;
#pragma unroll
        for (int i = 0; i < 3; ++i)
            *(ushort8*)&sRELV[e * 104 + i * 32 + p * 8] = url[i];
    }

    const int lane = t & 63;
    const int w = t >> 6;
    const int r0 = lane & 15;
    const int quad = lane >> 4;
    const int colw = w * 32;               // this wave's output-col base

    const short8* W0f   = (const short8*)W0b;
    const short8* Wm1f  = (const short8*)Wm1b;
    const short8* Wm2f  = (const short8*)Wm2b;
    const short8* Wm3f  = (const short8*)Wm3b;
    const short8* W011f = (const short8*)W011b;
    const short8* W101f = (const short8*)W101b;
    const short8* W111f = (const short8*)W111b;

    // ---- psi_v (row-tiled, wave-local rows; BEFORE any barrier) ----
    // reads own-wave sY0/sRELV/sRS rows (written by this wave in phase 1),
    // then overwrites own-wave sRELV rows with psi_v results (col i*32+d).
    {
        const int arow = w * 16 + r0;
        short8 aY0 = *(const short8*)&sY0[arow * 72 + quad * 8];
        short8 aRL[3];
#pragma unroll
        for (int i = 0; i < 3; ++i)
            aRL[i] = *(const short8*)&sRELV[arow * 104 + i * 32 + quad * 8];

#pragma unroll
        for (int nt = 0; nt < 2; ++nt) {
            short8 b011 = W011f[nt * 64 + lane];
            short8 b111 = W111f[nt * 64 + lane];
            short8 b101 = W101f[nt * 64 + lane];
            f32x4 sA = MFMA(aY0, b011, (f32x4){0.f, 0.f, 0.f, 0.f}, 0, 0, 0);
            f32x4 U[3], T[3];
#pragma unroll
            for (int i = 0; i < 3; ++i) {
                U[i] = MFMA(aRL[i], b111, (f32x4){0.f, 0.f, 0.f, 0.f}, 0, 0, 0);
                T[i] = MFMA(aRL[i], b101, (f32x4){0.f, 0.f, 0.f, 0.f}, 0, 0, 0);
            }
            int d = nt * 16 + r0;
#pragma unroll
            for (int rr = 0; rr < 4; ++rr) {
                int el = w * 16 + quad * 4 + rr;
                float4 rsv = *(const float4*)&sRS[el * 4];
                float s = sA[rr];
                float ux = U[0][rr], uy = U[1][rr], uz = U[2][rr];
                float ox = s * rsv.x + T[0][rr] + uy * rsv.z - uz * rsv.y;
                float oy = s * rsv.y + T[1][rr] + uz * rsv.x - ux * rsv.z;
                float oz = s * rsv.z + T[2][rr] + ux * rsv.y - uy * rsv.x;
                sRELV[el * 104 + 0 * 32 + d] = f2bf(ox);
                sRELV[el * 104 + 1 * 32 + d] = f2bf(oy);
                sRELV[el * 104 + 2 * 32 + d] = f2bf(oz);
            }
        }
    }

    __syncthreads();                       // B1: features + psi_v visible

    // ---- psi0 = Y0 @ W0cat^T (K=64), col-tiled: cols [colw, colw+32) ----
    f32x4 p0[4][2];
#pragma unroll
    for (int nt2 = 0; nt2 < 2; ++nt2) {
        short8 Bk0 = W0f[((w * 2 + nt2) * 2 + 0) * 64 + lane];
        short8 Bk1 = W0f[((w * 2 + nt2) * 2 + 1) * 64 + lane];
#pragma unroll
        for (int g = 0; g < 4; ++g) {
            short8 a0 = *(const short8*)&sY0[(g * 16 + r0) * 72 + quad * 8];
            short8 a1 = *(const short8*)&sY0[(g * 16 + r0) * 72 + 32 + quad * 8];
            f32x4 acc = {0.f, 0.f, 0.f, 0.f};
            acc = MFMA(a0, Bk0, acc, 0, 0, 0);
            acc = MFMA(a1, Bk1, acc, 0, 0, 0);
            p0[g][nt2] = acc;
#pragma unroll
            for (int rr = 0; rr < 4; ++rr)
                sACT[(g * 16 + quad * 4 + rr) * 136 + colw + nt2 * 16 + r0] =
                    f2bf(acc[rr]);
        }
    }
    __syncthreads();                       // B2: psi0 activations ready

    // ---- h1 = leaky(act @ Wm1^T + bm1): compute, barrier, write, barrier ----
    f32x4 hv[2][4];
#pragma unroll
    for (int nt2 = 0; nt2 < 2; ++nt2) {
        short8 Bw[4];
#pragma unroll
        for (int kb = 0; kb < 4; ++kb)
            Bw[kb] = Wm1f[((w * 2 + nt2) * 4 + kb) * 64 + lane];
        float bv = bm1[colw + nt2 * 16 + r0];
#pragma unroll
        for (int g = 0; g < 4; ++g) {
            f32x4 acc = {bv, bv, bv, bv};
#pragma unroll
            for (int kb = 0; kb < 4; ++kb) {
                short8 a = *(const short8*)&sACT[(g * 16 + r0) * 136 + kb * 32 + quad * 8];
                acc = MFMA(a, Bw[kb], acc, 0, 0, 0);
            }
#pragma unroll
            for (int rr = 0; rr < 4; ++rr) acc[rr] = leaky(acc[rr]);
            hv[nt2][g] = acc;
        }
    }
    __syncthreads();                       // B3a: psi0 reads complete
#pragma unroll
    for (int nt2 = 0; nt2 < 2; ++nt2)
#pragma unroll
        for (int g = 0; g < 4; ++g)
#pragma unroll
            for (int rr = 0; rr < 4; ++rr)
                sACT[(g * 16 + quad * 4 + rr) * 136 + colw + nt2 * 16 + r0] =
                    f2bf(hv[nt2][g][rr]);
    __syncthreads();                       // B3b: h1 ready

    // ---- h2 = leaky(act @ Wm2^T + bm2) ----
#pragma unroll
    for (int nt2 = 0; nt2 < 2; ++nt2) {
        short8 Bw[4];
#pragma unroll
        for (int kb = 0; kb < 4; ++kb)
            Bw[kb] = Wm2f[((w * 2 + nt2) * 4 + kb) * 64 + lane];
        float bv = bm2[colw + nt2 * 16 + r0];
#pragma unroll
        for (int g = 0; g < 4; ++g) {
            f32x4 acc = {bv, bv, bv, bv};
#pragma unroll
            for (int kb = 0; kb < 4; ++kb) {
                short8 a = *(const short8*)&sACT[(g * 16 + r0) * 136 + kb * 32 + quad * 8];
                acc = MFMA(a, Bw[kb], acc, 0, 0, 0);
            }
#pragma unroll
            for (int rr = 0; rr < 4; ++rr) acc[rr] = leaky(acc[rr]);
            hv[nt2][g] = acc;
        }
    }
    __syncthreads();                       // B4a: h1 reads complete
#pragma unroll
    for (int nt2 = 0; nt2 < 2; ++nt2)
#pragma unroll
        for (int g = 0; g < 4; ++g)
#pragma unroll
            for (int rr = 0; rr < 4; ++rr)
                sACT[(g * 16 + quad * 4 + rr) * 136 + colw + nt2 * 16 + r0] =
                    f2bf(hv[nt2][g][rr]);
    __syncthreads();                       // B4b: h2 ready

    // ---- psi_a = psi0 + h2 @ Wm3^T: compute in regs, then stage to sACT ----
    f32x4 fv[2][4];
#pragma unroll
    for (int nt2 = 0; nt2 < 2; ++nt2) {
        short8 Bw[4];
#pragma unroll
        for (int kb = 0; kb < 4; ++kb)
            Bw[kb] = Wm3f[((w * 2 + nt2) * 4 + kb) * 64 + lane];
#pragma unroll
        for (int g = 0; g < 4; ++g) {
            f32x4 acc = {0.f, 0.f, 0.f, 0.f};
#pragma unroll
            for (int kb = 0; kb < 4; ++kb) {
                short8 a = *(const short8*)&sACT[(g * 16 + r0) * 136 + kb * 32 + quad * 8];
                acc = MFMA(a, Bw[kb], acc, 0, 0, 0);
            }
#pragma unroll
            for (int rr = 0; rr < 4; ++rr) acc[rr] += p0[g][nt2][rr];
            fv[nt2][g] = acc;
        }
    }
    __syncthreads();                       // B5a: all h2 reads complete
#pragma unroll
    for (int nt2 = 0; nt2 < 2; ++nt2)
#pragma unroll
        for (int g = 0; g < 4; ++g)
#pragma unroll
            for (int rr = 0; rr < 4; ++rr)
                sACT[(g * 16 + quad * 4 + rr) * 136 + colw + nt2 * 16 + r0] =
                    f2bf(fv[nt2][g][rr]);
    __syncthreads();                       // B5b: psi_a (sACT) + psi_v (sRELV)

    // ---- fused segmented reduction over the block's src-sorted edges ----
    // thread t<128: psi_a col t; t in [128,224): psi_v col t-128 (= i*32+d).
    // interior runs -> plain store; runs touching block edge -> atomicAdd.
    {
        const int nE = min(EB, N_EDGES - e0);
        if (t < 224) {
            const bool isA = (t < 128);
            const int j = isA ? t : t - 128;
            const int dcol = j & 31, icol = j >> 5;
            float acc = 0.f;
            int cur = __float_as_int(sRS[3]);   // src id of edge 0
            int runstart = 0;
            for (int el = 0; el < nE; ++el) {
                int s = __float_as_int(sRS[el * 4 + 3]);
                if (s != cur) {
                    float v = 0.1f * acc;
                    if (isA) {
                        float* p = B_a + (size_t)cur * 128 + j;
                        if (runstart == 0) atomicAdd(p, v); else *p = v;
                    } else {
                        float* p = B_v + (size_t)cur * 96 + dcol * 3 + icol;
                        if (runstart == 0) atomicAdd(p, v); else *p = v;
                    }
                    acc = 0.f; cur = s; runstart = el;
                }
                acc += isA ? bf2f(sACT[el * 136 + j])
                           : bf2f(sRELV[el * 104 + j]);
            }
            float v = 0.1f * acc;              // last run: always boundary
            if (isA) atomicAdd(B_a + (size_t)cur * 128 + j, v);
            else     atomicAdd(B_v + (size_t)cur * 96 + dcol * 3 + icol, v);
        }
    }
}

extern "C" void kernel_launch(void* const* d_in, const int* in_sizes, int n_in,
                              void* d_out, int out_size, void* d_ws, size_t ws_size,
                              hipStream_t stream) {
    const float* x_a   = (const float*)d_in[0];
    const float* x_v   = (const float*)d_in[1];
    const float* r_ij  = (const float*)d_in[2];
    const int*   src   = (const int*)d_in[3];
    const int*   dst   = (const int*)d_in[4];
    const float* W_L0  = (const float*)d_in[5];
    const float* W_L1  = (const float*)d_in[6];
    const float* W_enc = (const float*)d_in[7];
    const float* b_enc = (const float*)d_in[8];
    const float* Wy000 = (const float*)d_in[9];
    const float* Wy110 = (const float*)d_in[10];
    const float* Wy011 = (const float*)d_in[11];
    const float* Wy101 = (const float*)d_in[12];
    const float* Wy111 = (const float*)d_in[13];
    const float* Wm1   = (const float*)d_in[14];
    const float* bm1   = (const float*)d_in[15];
    const float* Wm2   = (const float*)d_in[16];
    const float* bm2   = (const float*)d_in[17];
    const float* Wm3   = (const float*)d_in[18];

    float* out = (float*)d_out;
    float* B_a = out;
    float* B_v = out + (size_t)N_NODES * DIM_A;

    char* w = (char*)d_ws;
    float* LN     = (float*)w;  w += (size_t)N_NODES * 128 * 4;   // 25.6 MB
    int*   degS   = (int*)w;    w += (size_t)N_NODES * 4;
    int*   offsS  = (int*)w;    w += (size_t)(N_NODES + 16) * 4;
    int*   curS   = (int*)w;    w += (size_t)N_NODES * 4;
    int*   excl   = (int*)w;    w += (size_t)N_NODES * 4;
    int*   bsum   = (int*)w;    w += 64 * 4;
    int*   srcIdS = (int*)w;    w += (size_t)N_EDGES * 4;
    float4* edgeS = (float4*)w; w += (size_t)N_EDGES * 16;
    ushort* W0b   = (ushort*)w; w += 128 * 64 * 2;
    ushort* Wm1b  = (ushort*)w; w += 128 * 128 * 2;
    ushort* Wm2b  = (ushort*)w; w += 128 * 128 * 2;
    ushort* Wm3b  = (ushort*)w; w += 128 * 128 * 2;
    ushort* W011b = (ushort*)w; w += 32 * 32 * 2;
    ushort* W101b = (ushort*)w; w += 32 * 32 * 2;
    ushort* W111b = (ushort*)w; w += 32 * 32 * 2;

    hipMemsetAsync(degS, 0, N_NODES * sizeof(int), stream);
    hipMemsetAsync(d_out, 0, out_size, stream);   // zero base for reduce

    convw_kernel<<<64, 256, 0, stream>>>(Wy000, Wy110, Wy011, Wy101, Wy111,
                                         Wm1, Wm2, Wm3,
                                         W0b, Wm1b, Wm2b, Wm3b, W011b, W101b, W111b);
    node_proj_kernel<<<(N_NODES + 7) / 8, 256, 0, stream>>>(x_a, x_v, W_L0, W_L1, LN);

    hist_kernel<<<(N_EDGES + 255) / 256, 256, 0, stream>>>(src, degS);

    scan1_kernel<<<SCAN_B, 1024, 0, stream>>>(degS, excl, bsum);
    scan2_kernel<<<1, 64, 0, stream>>>(bsum);
    scan3_kernel<<<SCAN_B, 1024, 0, stream>>>(excl, bsum, offsS, curS);

    scatter_kernel<<<(N_EDGES + 255) / 256, 256, 0, stream>>>(src, dst, r_ij, curS,
                                                              edgeS, srcIdS);

    edge_mfma_kernel<<<(N_EDGES + EB - 1) / EB, 256, 0, stream>>>(
        edgeS, srcIdS, LN, W_enc, b_enc,
        W0b, Wm1b, Wm2b, Wm3b, W011b, W101b, W111b,
        bm1, bm2, B_a, B_v);
}

// Round 4
// 471.037 us; speedup vs baseline: 2.0548x; 1.0992x over previous
//
#include <hip/hip_runtime.h>
#include <hip/hip_bf16.h>

#define N_NODES 50000
#define N_EDGES 500000
#define DIM_A 128
#define DIM_V 32
#define CHAN 32
#define EB 64            // edges per block in edge kernel
#define SCAN_B 49        // ceil(50000/1024)

typedef __attribute__((ext_vector_type(8))) short short8;
typedef __attribute__((ext_vector_type(8))) unsigned short ushort8;
typedef __attribute__((ext_vector_type(4))) float f32x4;
typedef unsigned short ushort;

#define MFMA __builtin_amdgcn_mfma_f32_16x16x32_bf16

__device__ __forceinline__ ushort f2bf(float x) {
    __hip_bfloat16 h = __float2bfloat16(x);
    return *reinterpret_cast<ushort*>(&h);
}
__device__ __forceinline__ float bf2f(ushort u) {
    union { float f; unsigned int i; } v; v.i = ((unsigned int)u) << 16; return v.f;
}
__device__ __forceinline__ float leaky(float x) {
    return x >= 0.f ? x : 0.1f * x;
}

// ---------------- fused prep: convw + node_proj + hist ----------------------
// Fragment packing: element W[o][c] (o = output col, c = K index) lives at
//   ushort idx = ((o>>4)*KB + (c>>5))*512 + ((c>>3)&3)*128 + (o&15)*8 + (c&7)
// so a wave's B-fragment (fixed nt=o>>4, kb=c>>5) is the contiguous 1KB chunk
//   frag_short8[ (nt*KB+kb)*64 + lane ]
__global__ __launch_bounds__(256) void prep_kernel(
    const float* __restrict__ x_a, const float* __restrict__ x_v,
    const float* __restrict__ W_L0, const float* __restrict__ W_L1,
    const int* __restrict__ src,
    const float* __restrict__ Wy000, const float* __restrict__ Wy110,
    const float* __restrict__ Wy011, const float* __restrict__ Wy101,
    const float* __restrict__ Wy111,
    const float* __restrict__ Wm1, const float* __restrict__ Wm2,
    const float* __restrict__ Wm3,
    float* __restrict__ LN, int* __restrict__ degS,
    ushort* __restrict__ W0b, ushort* __restrict__ Wm1b,
    ushort* __restrict__ Wm2b, ushort* __restrict__ Wm3b,
    ushort* __restrict__ W011b, ushort* __restrict__ W101b,
    ushort* __restrict__ W111b)
{
    const int t = threadIdx.x;
    const int g = blockIdx.x * 256 + t;

    // --- histogram (grid covers 1.6M >= N_EDGES) ---
    if (g < N_EDGES) atomicAdd(&degS[src[g]], 1);

    // --- weight conversion (blocks 0..63) ---
    if (g < 128 * 128) {          // [128][128] matrices, KB=4
        int o = g >> 7, c = g & 127;
        int pi = ((o >> 4) * 4 + (c >> 5)) * 512 + ((c >> 3) & 3) * 128
               + (o & 15) * 8 + (c & 7);
        Wm1b[pi] = f2bf(Wm1[g]);
        Wm2b[pi] = f2bf(Wm2[g]);
        Wm3b[pi] = f2bf(Wm3[g]);
    }
    if (g < 128 * 64) {           // W0cat [128][64], KB=2; c<32 Wy000 else Wy110
        int o = g >> 6, c = g & 63;
        float v = (c < 32) ? Wy000[o * 32 + c] : Wy110[o * 32 + (c - 32)];
        int pi = ((o >> 4) * 2 + (c >> 5)) * 512 + ((c >> 3) & 3) * 128
               + (o & 15) * 8 + (c & 7);
        W0b[pi] = f2bf(v);
    }
    if (g < 32 * 32) {            // [32][32] matrices, KB=1
        int o = g >> 5, c = g & 31;
        int pi = (o >> 4) * 512 + ((c >> 3) & 3) * 128 + (o & 15) * 8 + (c & 7);
        W011b[pi] = f2bf(Wy011[g]);
        W101b[pi] = f2bf(Wy101[g]);
        W111b[pi] = f2bf(Wy111[g]);
    }

    // --- node projection: LN[n][128] = [L0(32) | L1(96, c*3+i)] ---
    // grid is exactly (N_NODES/8) blocks -> n always < N_NODES
    const int n = blockIdx.x * 8 + (t >> 5);
    const int c = t & 31;

    const float4* xa = (const float4*)(x_a + (size_t)n * DIM_A);
    const float4* w0 = (const float4*)(W_L0 + c * DIM_A);
    float acc = 0.f;
#pragma unroll 8
    for (int k = 0; k < DIM_A / 4; ++k) {
        float4 x = xa[k]; float4 w = w0[k];
        acc += x.x * w.x + x.y * w.y + x.z * w.z + x.w * w.w;
    }
    LN[(size_t)n * 128 + c] = acc;

    const float* xv = x_v + (size_t)n * DIM_V * 3;
    const float* w1 = W_L1 + c * DIM_V;
    float a0 = 0.f, a1 = 0.f, a2 = 0.f;
#pragma unroll 8
    for (int d = 0; d < DIM_V; ++d) {
        float w = w1[d];
        a0 += xv[d * 3 + 0] * w;
        a1 += xv[d * 3 + 1] * w;
        a2 += xv[d * 3 + 2] * w;
    }
    float* o = LN + (size_t)n * 128 + 32 + c * 3;
    o[0] = a0; o[1] = a1; o[2] = a2;
}

// ---------------- scan phase 1: per-1024-block inclusive scan ---------------
__global__ __launch_bounds__(1024) void scan1_kernel(const int* __restrict__ deg,
                                                     int* __restrict__ excl,
                                                     int* __restrict__ bsum)
{
    __shared__ int buf[1024];
    int t = threadIdx.x;
    int i = blockIdx.x * 1024 + t;
    int v = (i < N_NODES) ? deg[i] : 0;
    buf[t] = v;
    __syncthreads();
    for (int off = 1; off < 1024; off <<= 1) {
        int x = (t >= off) ? buf[t - off] : 0;
        __syncthreads();
        buf[t] += x;
        __syncthreads();
    }
    if (i < N_NODES) excl[i] = buf[t] - v;
    if (t == 1023) bsum[blockIdx.x] = buf[1023];
}

// ---------------- scan phase 2 (fused): add bsum prefix, write offs/cursor --
__global__ __launch_bounds__(1024) void scan3_kernel(const int* __restrict__ excl,
                                                     const int* __restrict__ bsum,
                                                     int* __restrict__ offs,
                                                     int* __restrict__ cursor)
{
    __shared__ int sOff;
    int t = threadIdx.x;
    if (t == 0) {                  // 49 independent L2-hit loads, unrolled
        int s = 0;
#pragma unroll
        for (int k = 0; k < SCAN_B; ++k)
            s += (k < blockIdx.x) ? bsum[k] : 0;
        sOff = s;
    }
    __syncthreads();
    int i = blockIdx.x * 1024 + t;
    if (i < N_NODES) {
        int o = excl[i] + sOff;
        offs[i] = o;
        cursor[i] = o;
    }
    if (i == 0) offs[N_NODES] = N_EDGES;
}

// ---------------- scatter: build src-sorted packed edge records -------------
__global__ __launch_bounds__(256) void scatter_kernel(
    const int* __restrict__ src, const int* __restrict__ dst,
    const float* __restrict__ r_ij, int* __restrict__ curS,
    float4* __restrict__ edgeS, int* __restrict__ srcIdS)
{
    int i = blockIdx.x * 256 + threadIdx.x;
    if (i < N_EDGES) {
        int s = src[i];
        int p = atomicAdd(&curS[s], 1);
        edgeS[p] = make_float4(r_ij[i * 3 + 0], r_ij[i * 3 + 1], r_ij[i * 3 + 2],
                               __int_as_float(dst[i]));
        srcIdS[p] = s;
    }
}

// ---------------- MFMA edge kernel, fused segmented reduction ---------------
// v5 (over v4): g-outer MLP loops (halve LDS A-fragment reads), weight-frag
// register prefetch one phase early (hide L2 latency behind compute; VGPR
// headroom to 128 is free at 4 blocks/CU), s_setprio around MFMA clusters,
// __expf-based transcendentals, NT interior reduction stores.
// LDS exactly 40960 B: sY0 9216 + sRELV 13312 + sACT 17408 + sRS 1024.
__global__ __launch_bounds__(256, 4) void edge_mfma_kernel(
    const float4* __restrict__ edgeS, const int* __restrict__ srcIdS,
    const float* __restrict__ LN,
    const float* __restrict__ W_enc, const float* __restrict__ b_enc,
    const ushort* __restrict__ W0b, const ushort* __restrict__ Wm1b,
    const ushort* __restrict__ Wm2b, const ushort* __restrict__ Wm3b,
    const ushort* __restrict__ W011b, const ushort* __restrict__ W101b,
    const ushort* __restrict__ W111b,
    const float* __restrict__ bm1, const float* __restrict__ bm2,
    float* __restrict__ B_a, float* __restrict__ B_v)
{
    __shared__ __align__(16) ushort sY0[64 * 72];     // [e][72]: 0..31 y000, 32..63 y110
    __shared__ __align__(16) ushort sRELV[64 * 104];  // [e]: in: re*lv_i; out: psi_v
    __shared__ __align__(16) ushort sACT[64 * 136];   // [e][136] act / final psi_a
    __shared__ __align__(16) float sRS[64 * 4];       // [e]: rsx,rsy,rsz,src-id-bits

    const int t = threadIdx.x;
    const int e0 = blockIdx.x * EB;

    // ---- phase 1: per-edge features -> LDS (wave-row partitioned) ----
    {
        const int e = t >> 2;          // wave w owns e in [16w,16w+16)
        const int p = t & 3;           // 8 channels each
        const int qe = min(e0 + e, N_EDGES - 1);
        f32x4 edv = __builtin_nontemporal_load((const f32x4*)edgeS + qe);
        int sid = __builtin_nontemporal_load(srcIdS + qe);
        float rx = edv[0], ry = edv[1], rz = edv[2];
        int dn = __float_as_int(edv[3]);
        float r = sqrtf(rx * rx + ry * ry + rz * rz);

        float rad[8];
#pragma unroll
        for (int k = 0; k < 8; ++k) {
            float d = (r - (5.0f / 7.0f) * (float)k) * 1.6f;
            rad[k] = __expf(-d * d);
        }
        float n14 = 1.4f * r;
        float ex = __expf(2.f * n14);
        float th = 1.f - 2.f / (ex + 1.f);          // tanh(n14), inf-safe
        float tt = th / fmaxf(n14, 1e-6f);
        float rsx = 1.4f * rx * tt, rsy = 1.4f * ry * tt, rsz = 1.4f * rz * tt;
        if (p == 0) {
            *(float4*)&sRS[e * 4] = make_float4(rsx, rsy, rsz, __int_as_float(sid));
        }

        float la[8];
        {
            const float4* lap = (const float4*)(LN + (size_t)dn * 128 + p * 8);
            float4 A = lap[0], B = lap[1];
            la[0] = A.x; la[1] = A.y; la[2] = A.z; la[3] = A.w;
            la[4] = B.x; la[5] = B.y; la[6] = B.z; la[7] = B.w;
        }
        float lv[24];
        {
            const float4* lvp = (const float4*)(LN + (size_t)dn * 128 + 32 + p * 24);
#pragma unroll
            for (int q = 0; q < 6; ++q) {
                float4 v = lvp[q];
                lv[q * 4 + 0] = v.x; lv[q * 4 + 1] = v.y;
                lv[q * 4 + 2] = v.z; lv[q * 4 + 3] = v.w;
            }
        }

        ushort8 u000, u110, url[3];
#pragma unroll
        for (int j = 0; j < 8; ++j) {
            int c = p * 8 + j;
            float re = b_enc[c];
#pragma unroll
            for (int k = 0; k < 8; ++k) re += rad[k] * W_enc[c * 8 + k];
            float lvx = lv[j * 3 + 0], lvy = lv[j * 3 + 1], lvz = lv[j * 3 + 2];
            float dotv = lvx * rsx + lvy * rsy + lvz * rsz;
            u000[j] = f2bf(la[j] * re);
            u110[j] = f2bf(re * dotv);
            url[0][j] = f2bf(re * lvx);
            url[1][j] = f2bf(re * lvy);
            url[2][j] = f2bf(re * lvz);
        }
        *(ushort8*)&sY0[e * 72 + p * 8]      = u000;
        *(ushort8*)&sY0[e * 72 + 32 + p * 8] = u110;
#pragma unroll
        for (int i = 0; i < 3; ++i)
            *(ushort8*)&sRELV[e * 104 + i * 32 + p * 8] = url[i];
    }

    const int lane = t & 63;
    const int w = t >> 6;
    const int r0 = lane & 15;
    const int quad = lane >> 4;
    const int colw = w * 32;               // this wave's output-col base

    const short8* W0f   = (const short8*)W0b;
    const short8* Wm1f  = (const short8*)Wm1b;
    const short8* Wm2f  = (const short8*)Wm2b;
    const short8* Wm3f  = (const short8*)Wm3b;
    const short8* W011f = (const short8*)W011b;
    const short8* W101f = (const short8*)W101b;
    const short8* W111f = (const short8*)W111b;

    // prefetch psi0 weights: latency hidden under psi_v MFMAs
    short8 W0r[2][2];
#pragma unroll
    for (int nt2 = 0; nt2 < 2; ++nt2) {
        W0r[nt2][0] = W0f[((w * 2 + nt2) * 2 + 0) * 64 + lane];
        W0r[nt2][1] = W0f[((w * 2 + nt2) * 2 + 1) * 64 + lane];
    }

    // ---- psi_v (row-tiled, wave-local rows; BEFORE any barrier) ----
    // reads own-wave sY0/sRELV/sRS rows (written by this wave in phase 1),
    // then overwrites own-wave sRELV rows with psi_v results (col i*32+d).
    {
        short8 b011[2], b111[2], b101[2];
#pragma unroll
        for (int nt = 0; nt < 2; ++nt) {
            b011[nt] = W011f[nt * 64 + lane];
            b111[nt] = W111f[nt * 64 + lane];
            b101[nt] = W101f[nt * 64 + lane];
        }
        const int arow = w * 16 + r0;
        short8 aY0 = *(const short8*)&sY0[arow * 72 + quad * 8];
        short8 aRL[3];
#pragma unroll
        for (int i = 0; i < 3; ++i)
            aRL[i] = *(const short8*)&sRELV[arow * 104 + i * 32 + quad * 8];

#pragma unroll
        for (int nt = 0; nt < 2; ++nt) {
            __builtin_amdgcn_s_setprio(1);
            f32x4 sA = MFMA(aY0, b011[nt], (f32x4){0.f, 0.f, 0.f, 0.f}, 0, 0, 0);
            f32x4 U[3], T[3];
#pragma unroll
            for (int i = 0; i < 3; ++i) {
                U[i] = MFMA(aRL[i], b111[nt], (f32x4){0.f, 0.f, 0.f, 0.f}, 0, 0, 0);
                T[i] = MFMA(aRL[i], b101[nt], (f32x4){0.f, 0.f, 0.f, 0.f}, 0, 0, 0);
            }
            __builtin_amdgcn_s_setprio(0);
            int d = nt * 16 + r0;
#pragma unroll
            for (int rr = 0; rr < 4; ++rr) {
                int el = w * 16 + quad * 4 + rr;
                float4 rsv = *(const float4*)&sRS[el * 4];
                float s = sA[rr];
                float ux = U[0][rr], uy = U[1][rr], uz = U[2][rr];
                float ox = s * rsv.x + T[0][rr] + uy * rsv.z - uz * rsv.y;
                float oy = s * rsv.y + T[1][rr] + uz * rsv.x - ux * rsv.z;
                float oz = s * rsv.z + T[2][rr] + ux * rsv.y - uy * rsv.x;
                sRELV[el * 104 + 0 * 32 + d] = f2bf(ox);
                sRELV[el * 104 + 1 * 32 + d] = f2bf(oy);
                sRELV[el * 104 + 2 * 32 + d] = f2bf(oz);
            }
        }
    }

    __syncthreads();                       // B1: features + psi_v visible

    // prefetch h1 weights: latency hidden under psi0 MFMAs
    short8 Wm1r[2][4];
#pragma unroll
    for (int nt2 = 0; nt2 < 2; ++nt2)
#pragma unroll
        for (int kb = 0; kb < 4; ++kb)
            Wm1r[nt2][kb] = Wm1f[((w * 2 + nt2) * 4 + kb) * 64 + lane];

    // ---- psi0 = Y0 @ W0cat^T (K=64), col-tiled, g-outer ----
    f32x4 p0[4][2];
    __builtin_amdgcn_s_setprio(1);
#pragma unroll
    for (int g = 0; g < 4; ++g) {
        short8 a0 = *(const short8*)&sY0[(g * 16 + r0) * 72 + quad * 8];
        short8 a1 = *(const short8*)&sY0[(g * 16 + r0) * 72 + 32 + quad * 8];
#pragma unroll
        for (int nt2 = 0; nt2 < 2; ++nt2) {
            f32x4 acc = {0.f, 0.f, 0.f, 0.f};
            acc = MFMA(a0, W0r[nt2][0], acc, 0, 0, 0);
            acc = MFMA(a1, W0r[nt2][1], acc, 0, 0, 0);
            p0[g][nt2] = acc;
#pragma unroll
            for (int rr = 0; rr < 4; ++rr)
                sACT[(g * 16 + quad * 4 + rr) * 136 + colw + nt2 * 16 + r0] =
                    f2bf(acc[rr]);
        }
    }
    __builtin_amdgcn_s_setprio(0);
    __syncthreads();                       // B2: psi0 activations ready

    // ---- h1 = leaky(act @ Wm1^T + bm1), g-outer ----
    f32x4 hv[2][4];
    {
        float bvA = bm1[colw + r0], bvB = bm1[colw + 16 + r0];
        __builtin_amdgcn_s_setprio(1);
#pragma unroll
        for (int g = 0; g < 4; ++g) {
            short8 af[4];
#pragma unroll
            for (int kb = 0; kb < 4; ++kb)
                af[kb] = *(const short8*)&sACT[(g * 16 + r0) * 136 + kb * 32 + quad * 8];
            f32x4 aA = {bvA, bvA, bvA, bvA};
            f32x4 aB = {bvB, bvB, bvB, bvB};
#pragma unroll
            for (int kb = 0; kb < 4; ++kb) {
                aA = MFMA(af[kb], Wm1r[0][kb], aA, 0, 0, 0);
                aB = MFMA(af[kb], Wm1r[1][kb], aB, 0, 0, 0);
            }
#pragma unroll
            for (int rr = 0; rr < 4; ++rr) { aA[rr] = leaky(aA[rr]); aB[rr] = leaky(aB[rr]); }
            hv[0][g] = aA; hv[1][g] = aB;
        }
        __builtin_amdgcn_s_setprio(0);
    }
    __syncthreads();                       // B3a: psi0 reads complete

    // prefetch h2 weights during h1 store region
    short8 Wm2r[2][4];
#pragma unroll
    for (int nt2 = 0; nt2 < 2; ++nt2)
#pragma unroll
        for (int kb = 0; kb < 4; ++kb)
            Wm2r[nt2][kb] = Wm2f[((w * 2 + nt2) * 4 + kb) * 64 + lane];

#pragma unroll
    for (int nt2 = 0; nt2 < 2; ++nt2)
#pragma unroll
        for (int g = 0; g < 4; ++g)
#pragma unroll
            for (int rr = 0; rr < 4; ++rr)
                sACT[(g * 16 + quad * 4 + rr) * 136 + colw + nt2 * 16 + r0] =
                    f2bf(hv[nt2][g][rr]);
    __syncthreads();                       // B3b: h1 ready

    // ---- h2 = leaky(act @ Wm2^T + bm2), g-outer ----
    {
        float bvA = bm2[colw + r0], bvB = bm2[colw + 16 + r0];
        __builtin_amdgcn_s_setprio(1);
#pragma unroll
        for (int g = 0; g < 4; ++g) {
            short8 af[4];
#pragma unroll
            for (int kb = 0; kb < 4; ++kb)
                af[kb] = *(const short8*)&sACT[(g * 16 + r0) * 136 + kb * 32 + quad * 8];
            f32x4 aA = {bvA, bvA, bvA, bvA};
            f32x4 aB = {bvB, bvB, bvB, bvB};
#pragma unroll
            for (int kb = 0; kb < 4; ++kb) {
                aA = MFMA(af[kb], Wm2r[0][kb], aA, 0, 0, 0);
                aB = MFMA(af[kb], Wm2r[1][kb], aB, 0, 0, 0);
            }
#pragma unroll
            for (int rr = 0; rr < 4; ++rr) { aA[rr] = leaky(aA[rr]); aB[rr] = leaky(aB[rr]); }
            hv[0][g] = aA; hv[1][g] = aB;
        }
        __builtin_amdgcn_s_setprio(0);
    }
    __syncthreads();                       // B4a: h1 reads complete

    // prefetch psi_a weights during h2 store region
    short8 Wm3r[2][4];
#pragma unroll
    for (int nt2 = 0; nt2 < 2; ++nt2)
#pragma unroll
        for (int kb = 0; kb < 4; ++kb)
            Wm3r[nt2][kb] = Wm3f[((w * 2 + nt2) * 4 + kb) * 64 + lane];

#pragma unroll
    for (int nt2 = 0; nt2 < 2; ++nt2)
#pragma unroll
        for (int g = 0; g < 4; ++g)
#pragma unroll
            for (int rr = 0; rr < 4; ++rr)
                sACT[(g * 16 + quad * 4 + rr) * 136 + colw + nt2 * 16 + r0] =
                    f2bf(hv[nt2][g][rr]);
    __syncthreads();                       // B4b: h2 ready

    // ---- psi_a = psi0 + h2 @ Wm3^T, g-outer ----
    f32x4 fv[2][4];
    __builtin_amdgcn_s_setprio(1);
#pragma unroll
    for (int g = 0; g < 4; ++g) {
        short8 af[4];
#pragma unroll
        for (int kb = 0; kb < 4; ++kb)
            af[kb] = *(const short8*)&sACT[(g * 16 + r0) * 136 + kb * 32 + quad * 8];
#pragma unroll
        for (int nt2 = 0; nt2 < 2; ++nt2) {
            f32x4 acc = {0.f, 0.f, 0.f, 0.f};
#pragma unroll
            for (int kb = 0; kb < 4; ++kb)
                acc = MFMA(af[kb], Wm3r[nt2][kb], acc, 0, 0, 0);
#pragma unroll
            for (int rr = 0; rr < 4; ++rr) acc[rr] += p0[g][nt2][rr];
            fv[nt2][g] = acc;
        }
    }
    __builtin_amdgcn_s_setprio(0);
    __syncthreads();                       // B5a: all h2 reads complete
#pragma unroll
    for (int nt2 = 0; nt2 < 2; ++nt2)
#pragma unroll
        for (int g = 0; g < 4; ++g)
#pragma unroll
            for (int rr = 0; rr < 4; ++rr)
                sACT[(g * 16 + quad * 4 + rr) * 136 + colw + nt2 * 16 + r0] =
                    f2bf(fv[nt2][g][rr]);
    __syncthreads();                       // B5b: psi_a (sACT) + psi_v (sRELV)

    // ---- fused segmented reduction over the block's src-sorted edges ----
    // thread t<128: psi_a col t; t in [128,224): psi_v col t-128 (= i*32+d).
    // interior runs -> NT store; runs touching block edge -> atomicAdd.
    {
        const int nE = min(EB, N_EDGES - e0);
        if (t < 224) {
            const bool isA = (t < 128);
            const int j = isA ? t : t - 128;
            const int dcol = j & 31, icol = j >> 5;
            float acc = 0.f;
            int cur = __float_as_int(sRS[3]);   // src id of edge 0
            int runstart = 0;
            for (int el = 0; el < nE; ++el) {
                int s = __float_as_int(sRS[el * 4 + 3]);
                if (s != cur) {
                    float v = 0.1f * acc;
                    float* p = isA ? (B_a + (size_t)cur * 128 + j)
                                   : (B_v + (size_t)cur * 96 + dcol * 3 + icol);
                    if (runstart == 0) atomicAdd(p, v);
                    else __builtin_nontemporal_store(v, p);
                    acc = 0.f; cur = s; runstart = el;
                }
                acc += isA ? bf2f(sACT[el * 136 + j])
                           : bf2f(sRELV[el * 104 + j]);
            }
            float v = 0.1f * acc;              // last run: always boundary
            if (isA) atomicAdd(B_a + (size_t)cur * 128 + j, v);
            else     atomicAdd(B_v + (size_t)cur * 96 + dcol * 3 + icol, v);
        }
    }
}

extern "C" void kernel_launch(void* const* d_in, const int* in_sizes, int n_in,
                              void* d_out, int out_size, void* d_ws, size_t ws_size,
                              hipStream_t stream) {
    const float* x_a   = (const float*)d_in[0];
    const float* x_v   = (const float*)d_in[1];
    const float* r_ij  = (const float*)d_in[2];
    const int*   src   = (const int*)d_in[3];
    const int*   dst   = (const int*)d_in[4];
    const float* W_L0  = (const float*)d_in[5];
    const float* W_L1  = (const float*)d_in[6];
    const float* W_enc = (const float*)d_in[7];
    const float* b_enc = (const float*)d_in[8];
    const float* Wy000 = (const float*)d_in[9];
    const float* Wy110 = (const float*)d_in[10];
    const float* Wy011 = (const float*)d_in[11];
    const float* Wy101 = (const float*)d_in[12];
    const float* Wy111 = (const float*)d_in[13];
    const float* Wm1   = (const float*)d_in[14];
    const float* bm1   = (const float*)d_in[15];
    const float* Wm2   = (const float*)d_in[16];
    const float* bm2   = (const float*)d_in[17];
    const float* Wm3   = (const float*)d_in[18];

    float* out = (float*)d_out;
    float* B_a = out;
    float* B_v = out + (size_t)N_NODES * DIM_A;

    char* w = (char*)d_ws;
    float* LN     = (float*)w;  w += (size_t)N_NODES * 128 * 4;   // 25.6 MB
    int*   degS   = (int*)w;    w += (size_t)N_NODES * 4;
    int*   offsS  = (int*)w;    w += (size_t)(N_NODES + 16) * 4;
    int*   curS   = (int*)w;    w += (size_t)N_NODES * 4;
    int*   excl   = (int*)w;    w += (size_t)N_NODES * 4;
    int*   bsum   = (int*)w;    w += 64 * 4;
    int*   srcIdS = (int*)w;    w += (size_t)N_EDGES * 4;
    float4* edgeS = (float4*)w; w += (size_t)N_EDGES * 16;
    ushort* W0b   = (ushort*)w; w += 128 * 64 * 2;
    ushort* Wm1b  = (ushort*)w; w += 128 * 128 * 2;
    ushort* Wm2b  = (ushort*)w; w += 128 * 128 * 2;
    ushort* Wm3b  = (ushort*)w; w += 128 * 128 * 2;
    ushort* W011b = (ushort*)w; w += 32 * 32 * 2;
    ushort* W101b = (ushort*)w; w += 32 * 32 * 2;
    ushort* W111b = (ushort*)w; w += 32 * 32 * 2;

    hipMemsetAsync(degS, 0, N_NODES * sizeof(int), stream);
    hipMemsetAsync(d_out, 0, out_size, stream);   // zero base for reduce

    prep_kernel<<<(N_NODES + 7) / 8, 256, 0, stream>>>(
        x_a, x_v, W_L0, W_L1, src,
        Wy000, Wy110, Wy011, Wy101, Wy111, Wm1, Wm2, Wm3,
        LN, degS, W0b, Wm1b, Wm2b, Wm3b, W011b, W101b, W111b);

    scan1_kernel<<<SCAN_B, 1024, 0, stream>>>(degS, excl, bsum);
    scan3_kernel<<<SCAN_B, 1024, 0, stream>>>(excl, bsum, offsS, curS);

    scatter_kernel<<<(N_EDGES + 255) / 256, 256, 0, stream>>>(src, dst, r_ij, curS,
                                                              edgeS, srcIdS);

    edge_mfma_kernel<<<(N_EDGES + EB - 1) / EB, 256, 0, stream>>>(
        edgeS, srcIdS, LN, W_enc, b_enc,
        W0b, Wm1b, Wm2b, Wm3b, W011b, W101b, W111b,
        bm1, bm2, B_a, B_v);
}